// Round 15
// baseline (425.926 us; speedup 1.0000x reference)
//
#include <hip/hip_runtime.h>
#include <hip/hip_bf16.h>
#include <stdint.h>

#define B_ 2
#define S_ 1024
#define D_ 2048
#define H_ 16
#define F_ 8192
#define DH_ 128
#define M_ 2048  // B*S

typedef unsigned short u16;
typedef __attribute__((ext_vector_type(8))) short short8;
typedef __attribute__((ext_vector_type(4))) float f32x4;

__device__ __forceinline__ u16 f2bf(float f) {
  union { float f; uint32_t u; } c; c.f = f;
  uint32_t r = c.u + 0x7FFFu + ((c.u >> 16) & 1u);
  return (u16)(r >> 16);
}

__device__ __forceinline__ float bf2f(u16 v) {
  union { uint32_t u; float f; } c; c.u = ((uint32_t)v) << 16;
  return c.f;
}

__device__ __forceinline__ void gload16(const void* g, void* l) {
  __builtin_amdgcn_global_load_lds((const __attribute__((address_space(1))) void*)g,
                                   (__attribute__((address_space(3))) void*)l, 16, 0, 0);
}

__device__ __forceinline__ float clipa(float a) {
  return fminf(0.2f, fmaxf(-0.2f, a));
}

__device__ __forceinline__ float gelu_f(float x) {
  float z = 0.7978845608028654f * (x + 0.044715f * x * x * x);
  z = fminf(10.f, fmaxf(-10.f, z));
  float e = __expf(2.f * z);
  return 0.5f * x * (1.f + (e - 1.f) / (e + 1.f));
}

// ---------------- CenterNorm ----------------
__global__ __launch_bounds__(256) void k_centernorm(const float* __restrict__ x,
                                                    const float* __restrict__ g,
                                                    const float* __restrict__ bb,
                                                    float* __restrict__ of,
                                                    u16* __restrict__ ob) {
  const int row = blockIdx.x;
  const int t = threadIdx.x;
  const float* xr = x + (size_t)row * D_;
  f32x4 v0 = *(const f32x4*)(xr + t * 8);
  f32x4 v1 = *(const f32x4*)(xr + t * 8 + 4);
  float s = v0[0] + v0[1] + v0[2] + v0[3] + v1[0] + v1[1] + v1[2] + v1[3];
#pragma unroll
  for (int off = 1; off < 64; off <<= 1) s += __shfl_xor(s, off);
  __shared__ float red[4];
  if ((t & 63) == 0) red[t >> 6] = s;
  __syncthreads();
  const float mu = (red[0] + red[1] + red[2] + red[3]) * (1.0f / D_);
  const float CNS = (float)D_ / (float)(D_ - 1);
  f32x4 g0 = *(const f32x4*)(g + t * 8);
  f32x4 g1 = *(const f32x4*)(g + t * 8 + 4);
  f32x4 b0 = *(const f32x4*)(bb + t * 8);
  f32x4 b1 = *(const f32x4*)(bb + t * 8 + 4);
  f32x4 y0, y1;
  short8 yb;
#pragma unroll
  for (int i = 0; i < 4; i++) {
    y0[i] = g0[i] * (CNS * (v0[i] - mu)) + b0[i];
    y1[i] = g1[i] * (CNS * (v1[i] - mu)) + b1[i];
  }
#pragma unroll
  for (int i = 0; i < 4; i++) { yb[i] = (short)f2bf(y0[i]); yb[4 + i] = (short)f2bf(y1[i]); }
  float* orow = of + (size_t)row * D_;
  *(f32x4*)(orow + t * 8) = y0;
  *(f32x4*)(orow + t * 8 + 4) = y1;
  *(short8*)(ob + (size_t)row * D_ + t * 8) = yb;
}

// ============ 256x256 GEMM (r9 schedule) with DIRECT-f32 B (reg-staged cvt) ============
// A: bf16 via gload_lds. B: f32 weights -> regs at q1, cvt+ds_write at q3 into the
// identical swizzled LDS image (read side unchanged). 512 thr: B chunks s*8192+t*16
// (4x8KB = full 32KB). End-of-tile: lgkmcnt(0)+vmcnt(0)+barrier.
// EPI 2: outb=bf16(gelu(acc+bias)) ; 3: outb=bf16(acc) ; 4: fused l2norm/tau for QKV.
template <int EPI>
__device__ __forceinline__ void gemm256_f32b(const u16* __restrict__ A,
                                             const float* __restrict__ Bt32,
                                             const float* __restrict__ bias,
                                             u16* __restrict__ outb,
                                             int N, int K, int kbase, int nk,
                                             int m0, int n0,
                                             const float* __restrict__ tau,
                                             u16* __restrict__ qkv, int z) {
  __shared__ char lds[2][65536];  // [buf][A 32KB | B 32KB]
  const int t = threadIdx.x;
  const int l = t & 63, w = t >> 6;
  const int wr = w >> 2, wc = w & 3;
  const int l15 = l & 15, lhi = l >> 4;
  const int sw = (l15 & 7) << 4;
  const int ab0 = l15 * 128 + ((lhi * 16) ^ sw);
  const int ab1 = l15 * 128 + ((64 + lhi * 16) ^ sw);

  auto stage_a = [&](int kt, int h) {
#pragma unroll
    for (int j = 0; j < 2; j++) {
      const int pl = h * 16384 + j * 8192 + t * 16;
      const int row = pl >> 7;
      const int scol = (pl & 127) ^ ((row & 7) << 4);
      const char* src = (const char*)A + (size_t)(m0 + row) * (size_t)(K * 2) +
                        (size_t)((kbase + kt * 64) * 2 + scol);
      gload16(src, &lds[kt & 1][pl]);
    }
  };

  f32x4 bld[8];
  auto stage_b_load = [&](int kt) {
#pragma unroll
    for (int s = 0; s < 4; s++) {
      const int pl = s * 8192 + t * 16;
      const int row = pl >> 7;
      const int scol = (pl & 127) ^ ((row & 7) << 4);  // bytes in bf16 space
      const float* src = Bt32 + (size_t)(n0 + row) * (size_t)K +
                         (size_t)(kbase + kt * 64 + (scol >> 1));
      bld[s * 2 + 0] = *(const f32x4*)(src);
      bld[s * 2 + 1] = *(const f32x4*)(src + 4);
    }
  };
  auto stage_b_write = [&](int kt) {
#pragma unroll
    for (int s = 0; s < 4; s++) {
      const int pl = s * 8192 + t * 16;
      short8 o;
#pragma unroll
      for (int e = 0; e < 4; e++) {
        o[e] = (short)f2bf(bld[s * 2][e]);
        o[4 + e] = (short)f2bf(bld[s * 2 + 1][e]);
      }
      *(short8*)(&lds[kt & 1][32768 + pl]) = o;
    }
  };

  f32x4 acc[8][4] = {};

  stage_b_load(0);
  stage_a(0, 0); stage_a(0, 1);
  stage_b_write(0);
  asm volatile("s_waitcnt vmcnt(0)" ::: "memory");
  asm volatile("s_waitcnt lgkmcnt(0)" ::: "memory");
  __builtin_amdgcn_s_barrier();
  __builtin_amdgcn_sched_barrier(0);

  for (int kt = 0; kt < nk; ++kt) {
    const char* base = &lds[kt & 1][0];
    const char* pA0 = base + wr * 4096 + ab0;
    const char* pA1 = base + wr * 4096 + ab1;
    const char* pB0 = base + 32768 + wc * 8192 + ab0;
    const char* pB1 = base + 32768 + wc * 8192 + ab1;
    const bool more = (kt + 1 < nk);
    short8 bf[4][2];
#pragma unroll
    for (int ni = 0; ni < 4; ni++) {
      bf[ni][0] = *(const short8*)(pB0 + ni * 2048);
      bf[ni][1] = *(const short8*)(pB1 + ni * 2048);
    }
#pragma unroll
    for (int q = 0; q < 4; q++) {
      short8 aq[2][2];
#pragma unroll
      for (int mi = 0; mi < 2; mi++) {
        aq[mi][0] = *(const short8*)(pA0 + q * 8192 + mi * 2048);
        aq[mi][1] = *(const short8*)(pA1 + q * 8192 + mi * 2048);
      }
      if (q == 1 && more) {
        stage_b_load(kt + 1);
        stage_a(kt + 1, 0);
        stage_a(kt + 1, 1);
      }
      if (q == 3 && more) stage_b_write(kt + 1);
      __builtin_amdgcn_s_setprio(1);
#pragma unroll
      for (int ks = 0; ks < 2; ks++)
#pragma unroll
        for (int mi = 0; mi < 2; mi++)
#pragma unroll
          for (int ni = 0; ni < 4; ni++)
            acc[q * 2 + mi][ni] = __builtin_amdgcn_mfma_f32_16x16x32_bf16(
                aq[mi][ks], bf[ni][ks], acc[q * 2 + mi][ni], 0, 0, 0);
      __builtin_amdgcn_s_setprio(0);
      if (q == 1) __builtin_amdgcn_s_barrier();
    }
    if (more) {
      asm volatile("s_waitcnt lgkmcnt(0)" ::: "memory");
      asm volatile("s_waitcnt vmcnt(0)" ::: "memory");
      __builtin_amdgcn_s_barrier();
      __builtin_amdgcn_sched_barrier(0);
    }
  }

  if constexpr (EPI == 4) {
    __shared__ float part[4][256];
#pragma unroll
    for (int ni = 0; ni < 4; ni++) {
      const float bc = bias[n0 + wc * 64 + ni * 16 + l15];
#pragma unroll
      for (int ai = 0; ai < 8; ai++)
#pragma unroll
        for (int j = 0; j < 4; j++) acc[ai][ni][j] += bc;
    }
    if (z < 2) {
      float p[8][4];
#pragma unroll
      for (int ai = 0; ai < 8; ai++)
#pragma unroll
        for (int j = 0; j < 4; j++) {
          p[ai][j] = acc[ai][0][j] * acc[ai][0][j] + acc[ai][1][j] * acc[ai][1][j] +
                     acc[ai][2][j] * acc[ai][2][j] + acc[ai][3][j] * acc[ai][3][j];
#pragma unroll
          for (int off = 1; off < 16; off <<= 1) p[ai][j] += __shfl_xor(p[ai][j], off);
        }
      if (l15 == 0) {
#pragma unroll
        for (int ai = 0; ai < 8; ai++)
#pragma unroll
          for (int j = 0; j < 4; j++) {
            const int rb = (ai >> 1) * 64 + wr * 32 + (ai & 1) * 16 + lhi * 4 + j;
            part[wc][rb] = p[ai][j];
          }
      }
    }
    __syncthreads();
    const int hl = wc >> 1;
    const int hglob = (n0 >> 7) + hl;
    const float tauh = (z == 0) ? tau[hglob] : 1.f;
    char* yt = (char*)&lds[0][0] + w * 16384;
#pragma unroll
    for (int ai = 0; ai < 8; ai++) {
#pragma unroll
      for (int j = 0; j < 4; j++) {
        float sc = 1.f;
        if (z < 2) {
          const int rb = (ai >> 1) * 64 + wr * 32 + (ai & 1) * 16 + lhi * 4 + j;
          const float ssq = part[2 * hl][rb] + part[2 * hl + 1][rb];
          sc = tauh / (sqrtf(ssq) + 1e-6f);
        }
        const int rl = (ai >> 1) * 32 + (ai & 1) * 16 + lhi * 4 + j;
        const int swz = (rl & 7) << 4;
#pragma unroll
        for (int ni = 0; ni < 4; ni++) {
          const int cbyte = (ni * 16 + l15) * 2;
          *(u16*)(yt + rl * 128 + (cbyte ^ swz)) = f2bf(acc[ai][ni][j] * sc);
        }
      }
    }
    __syncthreads();
#pragma unroll
    for (int pass = 0; pass < 16; pass++) {
      const int rl = pass * 8 + (l >> 3);
      const int cb = (l & 7) * 16;
      const short8 v = *(const short8*)(yt + rl * 128 + (cb ^ ((rl & 7) << 4)));
      const int m = m0 + ((rl >> 5) << 6) + wr * 32 + (rl & 31);
      const int bb2 = m >> 10, s = m & 1023;
      const int d = (wc & 1) * 64 + (cb >> 1);
      *(short8*)(qkv + (((size_t)(bb2 * H_ + hglob)) * S_ + s) * DH_ + d) = v;
    }
    return;
  }

#pragma unroll
  for (int ni = 0; ni < 4; ni++) {
    const int col = n0 + wc * 64 + ni * 16 + l15;
    const float bcol = (EPI == 3) ? 0.f : bias[col];
#pragma unroll
    for (int ai = 0; ai < 8; ai++) {
      const int row = m0 + (ai >> 1) * 64 + wr * 32 + (ai & 1) * 16 + lhi * 4;
#pragma unroll
      for (int j = 0; j < 4; j++) {
        const float v = acc[ai][ni][j] + bcol;
        const size_t idx = (size_t)(row + j) * N + col;
        if (EPI == 2) outb[idx] = f2bf(gelu_f(v));
        else outb[idx] = f2bf(v);
      }
    }
  }
}

__global__ __launch_bounds__(512, 2) void k_qkv256(const u16* A, const float* wq,
                                                   const float* wk, const float* wv,
                                                   const float* b0, const float* b1,
                                                   const float* b2, const float* tau,
                                                   u16* qn, u16* kn, u16* vn) {
  const int z = blockIdx.z;
  const float* Bt = z == 0 ? wq : (z == 1 ? wk : wv);
  const float* bias = z == 0 ? b0 : (z == 1 ? b1 : b2);
  u16* dst = z == 0 ? qn : (z == 1 ? kn : vn);
  gemm256_f32b<4>(A, Bt, bias, nullptr, D_, D_, 0, 32,
                  blockIdx.y * 256, blockIdx.x * 256, tau, dst, z);
}

__global__ __launch_bounds__(512, 2) void k_ffn1_256(const u16* A, const float* w1,
                                                     const float* bias, u16* outb) {
  gemm256_f32b<2>(A, w1, bias, outb, F_, D_, 0, 32,
                  blockIdx.y * 256, blockIdx.x * 256, nullptr, nullptr, 0);
}

__global__ __launch_bounds__(512, 2) void k_ffn2_256(const u16* A, const float* w2, u16* P) {
  gemm256_f32b<3>(A, w2, nullptr, P + (size_t)blockIdx.z * M_ * D_, D_, F_,
                  blockIdx.z * 2048, 32, blockIdx.y * 256, blockIdx.x * 256,
                  nullptr, nullptr, 0);
}

// ---------- 128x128 deep-pipelined GEMM (4 waves, 256 thr) with direct-f32 B: o-proj ----
// FIX vs r14: B chunks must be s*4096+t*16, s in 0..3 (256thr x 16B = 4KB/chunk; r14's
// s*8192 stride covered only half the 16KB B tile -> stale LDS -> absmax 13.5).
__global__ __launch_bounds__(256, 2) void k_oproj(const u16* __restrict__ A,
                                                  const float* __restrict__ Bt32,
                                                  const float* __restrict__ bias,
                                                  const float* __restrict__ res,
                                                  const float* __restrict__ alpha,
                                                  float* __restrict__ outf) {
  const int N = D_, K = D_, nk = 32;
  const int m0 = blockIdx.y * 128, n0 = blockIdx.x * 128;
  __shared__ char lds[2][32768];  // [buf][A 16KB | B 16KB]
  const int t = threadIdx.x;
  const int l = t & 63, w = t >> 6;
  const int wr = w >> 1, wc = w & 1;
  const int l15 = l & 15, lhi = l >> 4;
  const int sw = (l15 & 7) << 4;
  const int ab0 = l15 * 128 + ((lhi * 16) ^ sw);
  const int ab1 = l15 * 128 + ((64 + lhi * 16) ^ sw);

  auto stage_a = [&](int kt, int h) {
#pragma unroll
    for (int j = 0; j < 2; j++) {
      const int pl = h * 8192 + j * 4096 + t * 16;
      const int row = pl >> 7;
      const int scol = (pl & 127) ^ ((row & 7) << 4);
      const char* src = (const char*)A + (size_t)(m0 + row) * (size_t)(K * 2) +
                        (size_t)(kt * 128 + scol);
      gload16(src, &lds[kt & 1][pl]);
    }
  };

  f32x4 bld[8];
  auto stage_b_load = [&](int kt) {
#pragma unroll
    for (int s = 0; s < 4; s++) {
      const int pl = s * 4096 + t * 16;
      const int row = pl >> 7;
      const int scol = (pl & 127) ^ ((row & 7) << 4);
      const float* src = Bt32 + (size_t)(n0 + row) * (size_t)K +
                         (size_t)(kt * 64 + (scol >> 1));
      bld[s * 2 + 0] = *(const f32x4*)(src);
      bld[s * 2 + 1] = *(const f32x4*)(src + 4);
    }
  };
  auto stage_b_write = [&](int kt) {
#pragma unroll
    for (int s = 0; s < 4; s++) {
      const int pl = s * 4096 + t * 16;
      short8 o;
#pragma unroll
      for (int e = 0; e < 4; e++) {
        o[e] = (short)f2bf(bld[s * 2][e]);
        o[4 + e] = (short)f2bf(bld[s * 2 + 1][e]);
      }
      *(short8*)(&lds[kt & 1][16384 + pl]) = o;
    }
  };

  f32x4 acc[4][4] = {};
  stage_b_load(0);
  stage_a(0, 0); stage_a(0, 1);
  stage_b_write(0);
  asm volatile("s_waitcnt vmcnt(0)" ::: "memory");
  asm volatile("s_waitcnt lgkmcnt(0)" ::: "memory");
  __builtin_amdgcn_s_barrier();
  __builtin_amdgcn_sched_barrier(0);

  for (int kt = 0; kt < nk; ++kt) {
    const char* base = &lds[kt & 1][0];
    const char* pB0 = base + 16384 + wc * 8192 + ab0;
    const char* pB1 = base + 16384 + wc * 8192 + ab1;
    const bool more = (kt + 1 < nk);
    short8 bf[4][2];
#pragma unroll
    for (int ni = 0; ni < 4; ni++) {
      bf[ni][0] = *(const short8*)(pB0 + ni * 2048);
      bf[ni][1] = *(const short8*)(pB1 + ni * 2048);
    }
#pragma unroll
    for (int q = 0; q < 2; q++) {
      short8 aq[2][2];
#pragma unroll
      for (int mi = 0; mi < 2; mi++) {
        aq[mi][0] = *(const short8*)(base + q * 8192 + wr * 4096 + mi * 2048 + ab0);
        aq[mi][1] = *(const short8*)(base + q * 8192 + wr * 4096 + mi * 2048 + ab1);
      }
      if (q == 0 && more) {
        stage_b_load(kt + 1);
        stage_a(kt + 1, 0);
        stage_a(kt + 1, 1);
      }
      if (q == 1 && more) stage_b_write(kt + 1);
      __builtin_amdgcn_s_setprio(1);
#pragma unroll
      for (int ks = 0; ks < 2; ks++)
#pragma unroll
        for (int mi = 0; mi < 2; mi++)
#pragma unroll
          for (int ni = 0; ni < 4; ni++)
            acc[q * 2 + mi][ni] = __builtin_amdgcn_mfma_f32_16x16x32_bf16(
                aq[mi][ks], bf[ni][ks], acc[q * 2 + mi][ni], 0, 0, 0);
      __builtin_amdgcn_s_setprio(0);
      if (q == 0) __builtin_amdgcn_s_barrier();
    }
    if (more) {
      asm volatile("s_waitcnt lgkmcnt(0)" ::: "memory");
      asm volatile("s_waitcnt vmcnt(0)" ::: "memory");
      __builtin_amdgcn_s_barrier();
      __builtin_amdgcn_sched_barrier(0);
    }
  }

#pragma unroll
  for (int ni = 0; ni < 4; ni++) {
    const int col = n0 + wc * 64 + ni * 16 + l15;
    const float bcol = bias[col];
    const float alc = clipa(alpha[col]);
#pragma unroll
    for (int ai = 0; ai < 4; ai++) {
      const int row = m0 + (ai >> 1) * 64 + wr * 32 + (ai & 1) * 16 + lhi * 4;
#pragma unroll
      for (int j = 0; j < 4; j++) {
        const size_t idx = (size_t)(row + j) * N + col;
        outf[idx] = res[idx] + alc * (acc[ai][ni][j] + bcol);
      }
    }
  }
}

// out = res + clip(alpha)*(sum_z P[z] + bias) ; P is bf16
__global__ __launch_bounds__(256) void k_ffn2_combine(const u16* __restrict__ P,
                                                      const float* __restrict__ bias,
                                                      const float* __restrict__ res,
                                                      const float* __restrict__ alpha,
                                                      float* __restrict__ out) {
  const int i = blockIdx.x * 256 + threadIdx.x;
  const size_t base = (size_t)i * 8;
  const int col = (int)(base & (D_ - 1));
  const size_t PS = (size_t)M_ * D_;
  float s[8] = {};
#pragma unroll
  for (int p = 0; p < 4; p++) {
    short8 v = *(const short8*)(P + p * PS + base);
#pragma unroll
    for (int j = 0; j < 8; j++) s[j] += bf2f((u16)v[j]);
  }
  f32x4 b0 = *(const f32x4*)(bias + col);
  f32x4 b1 = *(const f32x4*)(bias + col + 4);
  f32x4 a0 = *(const f32x4*)(alpha + col);
  f32x4 a1 = *(const f32x4*)(alpha + col + 4);
  f32x4 r0 = *(const f32x4*)(res + base);
  f32x4 r1 = *(const f32x4*)(res + base + 4);
  f32x4 o0, o1;
#pragma unroll
  for (int j = 0; j < 4; j++) {
    o0[j] = r0[j] + clipa(a0[j]) * (s[j] + b0[j]);
    o1[j] = r1[j] + clipa(a1[j]) * (s[4 + j] + b1[j]);
  }
  *(f32x4*)(out + base) = o0;
  *(f32x4*)(out + base + 4) = o1;
}

// ---------------- attention: cosine attn (Q pre-scaled by tau), causal ----------------
__global__ __launch_bounds__(256) void k_attn(const u16* __restrict__ qn,
                                              const u16* __restrict__ kn,
                                              const u16* __restrict__ vn,
                                              const float* __restrict__ nu,
                                              u16* __restrict__ o) {
  __shared__ u16 Ks[64 * 128];
  __shared__ u16 Vt[128 * 64];
  __shared__ u16 Pl[4][16][72];
  const int t = threadIdx.x;
  const int l = t & 63, w = t >> 6;
  const int l15 = l & 15, lhi = l >> 4;
  const int qt = blockIdx.x;
  const int bh = blockIdx.y;
  const int h = bh & (H_ - 1);
  const int b = bh >> 4;
  const size_t hoff = (size_t)bh * S_ * DH_;
  const u16* Qh = qn + hoff;
  const u16* Kh = kn + hoff;
  const u16* Vh = vn + hoff;
  const int q0 = qt * 64;
  const int r0 = q0 + w * 16;
  short8 qf[4];
#pragma unroll
  for (int kk = 0; kk < 4; kk++)
    qf[kk] = *(const short8*)(Qh + (size_t)(r0 + l15) * DH_ + kk * 32 + lhi * 8);
  float mrow[4], lrow[4];
  f32x4 oacc[8] = {};
#pragma unroll
  for (int j = 0; j < 4; j++) { mrow[j] = -1e30f; lrow[j] = 0.f; }

  for (int kv0 = 0; kv0 < q0 + 64; kv0 += 64) {
#pragma unroll
    for (int i = 0; i < 4; i++) {
      const int p = i * 4096 + t * 16;
      const int row = p >> 8;
      const int colb = p & 255;
      const int scolb = colb ^ ((row & 7) << 4);
      gload16((const char*)(Kh + (size_t)(kv0 + row) * DH_) + scolb, (char*)Ks + p);
    }
#pragma unroll
    for (int i = 0; i < 4; i++) {
      const int c0 = w * 8 + i * 32;
      const int r = l;
      short8 vv = *(const short8*)(Vh + (size_t)(kv0 + r) * DH_ + c0);
#pragma unroll
      for (int j = 0; j < 8; j++) {
        const int ba = ((c0 + j) * 128 + r * 2) ^ (((c0 + j) & 7) << 4);
        *(u16*)((char*)Vt + ba) = (u16)vv[j];
      }
    }
    __syncthreads();
    f32x4 st[4] = {};
#pragma unroll
    for (int ks = 0; ks < 4; ks++) {
#pragma unroll
      for (int ct = 0; ct < 4; ct++) {
        const int n = ct * 16 + l15;
        const int ka = (ks * 32 + lhi * 8) * 2;
        short8 kf = *(const short8*)((const char*)Ks + n * 256 + (ka ^ ((n & 7) << 4)));
        st[ct] = __builtin_amdgcn_mfma_f32_16x16x32_bf16(qf[ks], kf, st[ct], 0, 0, 0);
      }
    }
    float pm[4] = {-1e30f, -1e30f, -1e30f, -1e30f};
#pragma unroll
    for (int ct = 0; ct < 4; ct++) {
      const int col = kv0 + ct * 16 + l15;
#pragma unroll
      for (int j = 0; j < 4; j++) {
        const int row = r0 + lhi * 4 + j;
        float s = st[ct][j];
        s = (col <= row) ? s : -1e30f;
        st[ct][j] = s;
        pm[j] = fmaxf(pm[j], s);
      }
    }
#pragma unroll
    for (int j = 0; j < 4; j++) {
#pragma unroll
      for (int off = 1; off < 16; off <<= 1) pm[j] = fmaxf(pm[j], __shfl_xor(pm[j], off));
    }
    float scl[4], psum[4];
#pragma unroll
    for (int j = 0; j < 4; j++) {
      const float nm = fmaxf(mrow[j], pm[j]);
      scl[j] = __expf(mrow[j] - nm);
      mrow[j] = nm;
      psum[j] = 0.f;
    }
#pragma unroll
    for (int ct = 0; ct < 4; ct++) {
#pragma unroll
      for (int j = 0; j < 4; j++) {
        const float p = __expf(st[ct][j] - mrow[j]);
        psum[j] += p;
        Pl[w][lhi * 4 + j][ct * 16 + l15] = f2bf(p);
      }
    }
#pragma unroll
    for (int j = 0; j < 4; j++) {
#pragma unroll
      for (int off = 1; off < 16; off <<= 1) psum[j] += __shfl_xor(psum[j], off);
      lrow[j] = lrow[j] * scl[j] + psum[j];
    }
#pragma unroll
    for (int nt = 0; nt < 8; nt++) {
#pragma unroll
      for (int j = 0; j < 4; j++) oacc[nt][j] *= scl[j];
    }
#pragma unroll
    for (int ks2 = 0; ks2 < 2; ks2++) {
      short8 pa = *(const short8*)((const char*)&Pl[w][0][0] + l15 * 144 + ks2 * 64 + lhi * 16);
#pragma unroll
      for (int nt = 0; nt < 8; nt++) {
        const int n = nt * 16 + l15;
        const int ba = (n * 128 + (ks2 * 32 + lhi * 8) * 2) ^ ((n & 7) << 4);
        short8 vf = *(const short8*)((const char*)Vt + ba);
        oacc[nt] = __builtin_amdgcn_mfma_f32_16x16x32_bf16(pa, vf, oacc[nt], 0, 0, 0);
      }
    }
    __syncthreads();
  }
  const float num = nu[h];
  float rs[4];
#pragma unroll
  for (int j = 0; j < 4; j++) rs[j] = num / lrow[j];
#pragma unroll
  for (int nt = 0; nt < 8; nt++) {
    const int col = h * DH_ + nt * 16 + l15;
#pragma unroll
    for (int j = 0; j < 4; j++) {
      const int row = r0 + lhi * 4 + j;
      o[((size_t)b * S_ + row) * D_ + col] = f2bf(oacc[nt][j] * rs[j]);
    }
  }
}

// ---------------- launch ----------------
extern "C" void kernel_launch(void* const* d_in, const int* in_sizes, int n_in,
                              void* d_out, int out_size, void* d_ws, size_t ws_size,
                              hipStream_t stream) {
  const float* x    = (const float*)d_in[0];
  const float* ln1g = (const float*)d_in[1];
  const float* ln1b = (const float*)d_in[2];
  const float* wq   = (const float*)d_in[3];
  const float* bq   = (const float*)d_in[4];
  const float* wk   = (const float*)d_in[5];
  const float* bk   = (const float*)d_in[6];
  const float* wv   = (const float*)d_in[7];
  const float* bv   = (const float*)d_in[8];
  const float* wo   = (const float*)d_in[9];
  const float* bo   = (const float*)d_in[10];
  const float* tau  = (const float*)d_in[11];
  const float* nu   = (const float*)d_in[12];
  const float* al1  = (const float*)d_in[13];
  const float* ln2g = (const float*)d_in[14];
  const float* ln2b = (const float*)d_in[15];
  const float* w1   = (const float*)d_in[16];
  const float* b1   = (const float*)d_in[17];
  const float* w2   = (const float*)d_in[18];
  const float* b2   = (const float*)d_in[19];
  const float* al2  = (const float*)d_in[20];

  char* ws = (char*)d_ws;
  u16*   P4 = (u16*)(ws + 0);             // ffn2 bf16 partials, 4x8MB
  u16*   HB = (u16*)(ws + 33554432);      // ffn hidden bf16 (32MB)
  float* AF = (float*)(ws + 100663296);   // centernorm1 f32
  u16*   AB = (u16*)(ws + 117440512);     // centernorm1 bf16
  u16*   OB = (u16*)(ws + 125829120);     // attn out bf16
  u16*   MB = (u16*)(ws + 134217728);     // centernorm2 bf16
  float* X1 = (float*)(ws + 142606336);   // residual1 f32
  float* MF2 = (float*)(ws + 159383552);  // centernorm2 f32
  u16* QN = (u16*)(ws + 176160768);
  u16* KN = (u16*)(ws + 184549376);
  u16* VN = (u16*)(ws + 192937984);

  // centernorm 1
  k_centernorm<<<M_, 256, 0, stream>>>(x, ln1g, ln1b, AF, AB);

  // qkv projections (direct f32 weights) + fused l2norm/tau/head-reorder
  k_qkv256<<<dim3(8, 8, 3), 512, 0, stream>>>(AB, wq, wk, wv, bq, bk, bv, tau, QN, KN, VN);

  // attention (tau folded into Q)
  k_attn<<<dim3(S_ / 64, B_ * H_), 256, 0, stream>>>(QN, KN, VN, nu, OB);

  // output projection + residual (x1 = a + a1*attn), direct f32 WO
  k_oproj<<<dim3(16, 16), 256, 0, stream>>>(OB, wo, bo, AF, al1, X1);

  // centernorm 2
  k_centernorm<<<M_, 256, 0, stream>>>(X1, ln2g, ln2b, MF2, MB);

  // ffn1 (gelu -> bf16), direct f32 W1
  k_ffn1_256<<<dim3(32, 8), 512, 0, stream>>>(MB, w1, b1, HB);

  // ffn2 split-K=4 bf16 partials + combine, direct f32 W2
  k_ffn2_256<<<dim3(8, 8, 4), 512, 0, stream>>>(HB, w2, P4);
  k_ffn2_combine<<<2048, 256, 0, stream>>>(P4, b2, MF2, al2, (float*)d_out);
}

// Round 16
// 373.124 us; speedup vs baseline: 1.1415x; 1.1415x over previous
//
#include <hip/hip_runtime.h>
#include <hip/hip_bf16.h>
#include <stdint.h>

#define B_ 2
#define S_ 1024
#define D_ 2048
#define H_ 16
#define F_ 8192
#define DH_ 128
#define M_ 2048  // B*S

typedef unsigned short u16;
typedef __attribute__((ext_vector_type(8))) short short8;
typedef __attribute__((ext_vector_type(4))) float f32x4;

__device__ __forceinline__ u16 f2bf(float f) {
  union { float f; uint32_t u; } c; c.f = f;
  uint32_t r = c.u + 0x7FFFu + ((c.u >> 16) & 1u);
  return (u16)(r >> 16);
}

__device__ __forceinline__ float bf2f(u16 v) {
  union { uint32_t u; float f; } c; c.u = ((uint32_t)v) << 16;
  return c.f;
}

__device__ __forceinline__ void gload16(const void* g, void* l) {
  __builtin_amdgcn_global_load_lds((const __attribute__((address_space(1))) void*)g,
                                   (__attribute__((address_space(3))) void*)l, 16, 0, 0);
}

__device__ __forceinline__ float clipa(float a) {
  return fminf(0.2f, fmaxf(-0.2f, a));
}

__device__ __forceinline__ float gelu_f(float x) {
  float z = 0.7978845608028654f * (x + 0.044715f * x * x * x);
  z = fminf(10.f, fmaxf(-10.f, z));
  float e = __expf(2.f * z);
  return 0.5f * x * (1.f + (e - 1.f) / (e + 1.f));
}

// ---------------- f32 -> bf16 weight convert, one-shot, two launches (measured best) ----
__global__ __launch_bounds__(256) void k_cvt_half(const float* __restrict__ wq,
                                                  const float* __restrict__ wk,
                                                  const float* __restrict__ wv,
                                                  const float* __restrict__ wo,
                                                  const float* __restrict__ w1,
                                                  const float* __restrict__ w2,
                                                  u16* __restrict__ dst, int base) {
  const int gi = base + blockIdx.x * 256 + threadIdx.x;
  const float* s;
  int off;
  if (gi < 2097152) {
    int r = gi >> 19;
    s = r == 0 ? wq : (r == 1 ? wk : (r == 2 ? wv : wo));
    off = gi & 524287;
  } else if (gi < 4194304) {
    s = w1; off = gi - 2097152;
  } else {
    s = w2; off = gi - 4194304;
  }
  f32x4 a = *(const f32x4*)(s + (size_t)off * 8);
  f32x4 b = *(const f32x4*)(s + (size_t)off * 8 + 4);
  short8 o;
  o[0] = (short)f2bf(a[0]); o[1] = (short)f2bf(a[1]);
  o[2] = (short)f2bf(a[2]); o[3] = (short)f2bf(a[3]);
  o[4] = (short)f2bf(b[0]); o[5] = (short)f2bf(b[1]);
  o[6] = (short)f2bf(b[2]); o[7] = (short)f2bf(b[3]);
  *(short8*)(dst + (size_t)gi * 8) = o;
}

// ---------------- CenterNorm ----------------
__global__ __launch_bounds__(256) void k_centernorm(const float* __restrict__ x,
                                                    const float* __restrict__ g,
                                                    const float* __restrict__ bb,
                                                    float* __restrict__ of,
                                                    u16* __restrict__ ob) {
  const int row = blockIdx.x;
  const int t = threadIdx.x;
  const float* xr = x + (size_t)row * D_;
  f32x4 v0 = *(const f32x4*)(xr + t * 8);
  f32x4 v1 = *(const f32x4*)(xr + t * 8 + 4);
  float s = v0[0] + v0[1] + v0[2] + v0[3] + v1[0] + v1[1] + v1[2] + v1[3];
#pragma unroll
  for (int off = 1; off < 64; off <<= 1) s += __shfl_xor(s, off);
  __shared__ float red[4];
  if ((t & 63) == 0) red[t >> 6] = s;
  __syncthreads();
  const float mu = (red[0] + red[1] + red[2] + red[3]) * (1.0f / D_);
  const float CNS = (float)D_ / (float)(D_ - 1);
  f32x4 g0 = *(const f32x4*)(g + t * 8);
  f32x4 g1 = *(const f32x4*)(g + t * 8 + 4);
  f32x4 b0 = *(const f32x4*)(bb + t * 8);
  f32x4 b1 = *(const f32x4*)(bb + t * 8 + 4);
  f32x4 y0, y1;
  short8 yb;
#pragma unroll
  for (int i = 0; i < 4; i++) {
    y0[i] = g0[i] * (CNS * (v0[i] - mu)) + b0[i];
    y1[i] = g1[i] * (CNS * (v1[i] - mu)) + b1[i];
  }
#pragma unroll
  for (int i = 0; i < 4; i++) { yb[i] = (short)f2bf(y0[i]); yb[4 + i] = (short)f2bf(y1[i]); }
  float* orow = of + (size_t)row * D_;
  *(f32x4*)(orow + t * 8) = y0;
  *(f32x4*)(orow + t * 8 + 4) = y1;
  *(short8*)(ob + (size_t)row * D_ + t * 8) = yb;
}

// ============ 256x256 GEMM (r9 core, measured best): half-tile staged, 2 barriers ============
// EPI 2: outb=bf16(gelu(acc+bias)) ; 3: outb=bf16(acc) ; 4: fused l2norm/tau for QKV.
template <int EPI>
__device__ __forceinline__ void gemm256_core(const u16* __restrict__ A,
                                             const u16* __restrict__ Bt,
                                             const float* __restrict__ bias,
                                             u16* __restrict__ outb,
                                             int N, int K, int kbase, int nk,
                                             int m0, int n0,
                                             const float* __restrict__ tau,
                                             u16* __restrict__ qkv, int z) {
  __shared__ char lds[2][65536];  // [buf][A 32KB | B 32KB]
  const int t = threadIdx.x;
  const int l = t & 63, w = t >> 6;
  const int wr = w >> 2, wc = w & 3;
  const int l15 = l & 15, lhi = l >> 4;
  const int sw = (l15 & 7) << 4;
  const int ab0 = l15 * 128 + ((lhi * 16) ^ sw);
  const int ab1 = l15 * 128 + ((64 + lhi * 16) ^ sw);

  auto stage = [&](int kt, int h) {
#pragma unroll
    for (int rj = 0; rj < 4; rj++) {
      const int region = rj >> 1, j = rj & 1;
      const int pl = h * 16384 + j * 8192 + t * 16;
      const int row = pl >> 7;
      const int scol = (pl & 127) ^ ((row & 7) << 4);
      const int grow = (region ? n0 : m0) + row;
      const char* src = (const char*)(region ? Bt : A) +
                        (size_t)grow * (size_t)(K * 2) +
                        (size_t)((kbase + kt * 64) * 2 + scol);
      gload16(src, &lds[kt & 1][region * 32768 + pl]);
    }
  };

  f32x4 acc[8][4] = {};

  stage(0, 0); stage(0, 1); stage(1, 0);
  asm volatile("s_waitcnt vmcnt(4)" ::: "memory");
  __builtin_amdgcn_s_barrier();
  __builtin_amdgcn_sched_barrier(0);

  for (int kt = 0; kt < nk; ++kt) {
    const char* base = &lds[kt & 1][0];
    const char* pA0 = base + wr * 4096 + ab0;
    const char* pA1 = base + wr * 4096 + ab1;
    const char* pB0 = base + 32768 + wc * 8192 + ab0;
    const char* pB1 = base + 32768 + wc * 8192 + ab1;
    short8 bf[4][2];
#pragma unroll
    for (int ni = 0; ni < 4; ni++) {
      bf[ni][0] = *(const short8*)(pB0 + ni * 2048);
      bf[ni][1] = *(const short8*)(pB1 + ni * 2048);
    }
#pragma unroll
    for (int q = 0; q < 4; q++) {
      short8 aq[2][2];
#pragma unroll
      for (int mi = 0; mi < 2; mi++) {
        aq[mi][0] = *(const short8*)(pA0 + q * 8192 + mi * 2048);
        aq[mi][1] = *(const short8*)(pA1 + q * 8192 + mi * 2048);
      }
      if (q == 1 && kt + 1 < nk) stage(kt + 1, 1);
      if (q == 3 && kt + 2 < nk) stage(kt + 2, 0);
      __builtin_amdgcn_s_setprio(1);
#pragma unroll
      for (int ks = 0; ks < 2; ks++)
#pragma unroll
        for (int mi = 0; mi < 2; mi++)
#pragma unroll
          for (int ni = 0; ni < 4; ni++)
            acc[q * 2 + mi][ni] = __builtin_amdgcn_mfma_f32_16x16x32_bf16(
                aq[mi][ks], bf[ni][ks], acc[q * 2 + mi][ni], 0, 0, 0);
      __builtin_amdgcn_s_setprio(0);
      if (q == 1) __builtin_amdgcn_s_barrier();
    }
    if (kt + 1 < nk) {
      if (kt + 2 < nk) { asm volatile("s_waitcnt vmcnt(4)" ::: "memory"); }
      else             { asm volatile("s_waitcnt vmcnt(0)" ::: "memory"); }
      __builtin_amdgcn_s_barrier();
      __builtin_amdgcn_sched_barrier(0);
    }
  }

  if constexpr (EPI == 4) {
    __shared__ float part[4][256];
#pragma unroll
    for (int ni = 0; ni < 4; ni++) {
      const float bc = bias[n0 + wc * 64 + ni * 16 + l15];
#pragma unroll
      for (int ai = 0; ai < 8; ai++)
#pragma unroll
        for (int j = 0; j < 4; j++) acc[ai][ni][j] += bc;
    }
    if (z < 2) {
      float p[8][4];
#pragma unroll
      for (int ai = 0; ai < 8; ai++)
#pragma unroll
        for (int j = 0; j < 4; j++) {
          p[ai][j] = acc[ai][0][j] * acc[ai][0][j] + acc[ai][1][j] * acc[ai][1][j] +
                     acc[ai][2][j] * acc[ai][2][j] + acc[ai][3][j] * acc[ai][3][j];
#pragma unroll
          for (int off = 1; off < 16; off <<= 1) p[ai][j] += __shfl_xor(p[ai][j], off);
        }
      if (l15 == 0) {
#pragma unroll
        for (int ai = 0; ai < 8; ai++)
#pragma unroll
          for (int j = 0; j < 4; j++) {
            const int rb = (ai >> 1) * 64 + wr * 32 + (ai & 1) * 16 + lhi * 4 + j;
            part[wc][rb] = p[ai][j];
          }
      }
    }
    __syncthreads();
    const int hl = wc >> 1;
    const int hglob = (n0 >> 7) + hl;
    const float tauh = (z == 0) ? tau[hglob] : 1.f;
    char* yt = (char*)&lds[0][0] + w * 16384;
#pragma unroll
    for (int ai = 0; ai < 8; ai++) {
#pragma unroll
      for (int j = 0; j < 4; j++) {
        float sc = 1.f;
        if (z < 2) {
          const int rb = (ai >> 1) * 64 + wr * 32 + (ai & 1) * 16 + lhi * 4 + j;
          const float ssq = part[2 * hl][rb] + part[2 * hl + 1][rb];
          sc = tauh / (sqrtf(ssq) + 1e-6f);
        }
        const int rl = (ai >> 1) * 32 + (ai & 1) * 16 + lhi * 4 + j;
        const int swz = (rl & 7) << 4;
#pragma unroll
        for (int ni = 0; ni < 4; ni++) {
          const int cbyte = (ni * 16 + l15) * 2;
          *(u16*)(yt + rl * 128 + (cbyte ^ swz)) = f2bf(acc[ai][ni][j] * sc);
        }
      }
    }
    __syncthreads();
#pragma unroll
    for (int pass = 0; pass < 16; pass++) {
      const int rl = pass * 8 + (l >> 3);
      const int cb = (l & 7) * 16;
      const short8 v = *(const short8*)(yt + rl * 128 + (cb ^ ((rl & 7) << 4)));
      const int m = m0 + ((rl >> 5) << 6) + wr * 32 + (rl & 31);
      const int bb2 = m >> 10, s = m & 1023;
      const int d = (wc & 1) * 64 + (cb >> 1);
      *(short8*)(qkv + (((size_t)(bb2 * H_ + hglob)) * S_ + s) * DH_ + d) = v;
    }
    return;
  }

#pragma unroll
  for (int ni = 0; ni < 4; ni++) {
    const int col = n0 + wc * 64 + ni * 16 + l15;
    const float bcol = (EPI == 3) ? 0.f : bias[col];
#pragma unroll
    for (int ai = 0; ai < 8; ai++) {
      const int row = m0 + (ai >> 1) * 64 + wr * 32 + (ai & 1) * 16 + lhi * 4;
#pragma unroll
      for (int j = 0; j < 4; j++) {
        const float v = acc[ai][ni][j] + bcol;
        const size_t idx = (size_t)(row + j) * N + col;
        if (EPI == 2) outb[idx] = f2bf(gelu_f(v));
        else outb[idx] = f2bf(v);
      }
    }
  }
}

// natural blockIdx mapping (explicit XCD swizzle measured WORSE: FETCH 49->135MB r4/r5)
__global__ __launch_bounds__(512, 2) void k_qkv256(const u16* A, const u16* W,
                                                   const float* b0, const float* b1,
                                                   const float* b2, const float* tau,
                                                   u16* qn, u16* kn, u16* vn) {
  const int z = blockIdx.z;
  const u16* Bt = W + (size_t)z * 4194304;
  const float* bias = z == 0 ? b0 : (z == 1 ? b1 : b2);
  u16* dst = z == 0 ? qn : (z == 1 ? kn : vn);
  gemm256_core<4>(A, Bt, bias, nullptr, D_, D_, 0, 32,
                  blockIdx.y * 256, blockIdx.x * 256, tau, dst, z);
}

__global__ __launch_bounds__(512, 2) void k_ffn1_256(const u16* A, const u16* Bt,
                                                     const float* bias, u16* outb) {
  gemm256_core<2>(A, Bt, bias, outb, F_, D_, 0, 32,
                  blockIdx.y * 256, blockIdx.x * 256, nullptr, nullptr, 0);
}

__global__ __launch_bounds__(512, 2) void k_ffn2_256(const u16* A, const u16* Bt, u16* P) {
  gemm256_core<3>(A, Bt, nullptr, P + (size_t)blockIdx.z * M_ * D_, D_, F_,
                  blockIdx.z * 2048, 32, blockIdx.y * 256, blockIdx.x * 256,
                  nullptr, nullptr, 0);
}

// ---------- 128x128 deep-pipelined GEMM (4 waves): o-proj residual (r12, measured) ----------
__global__ __launch_bounds__(256, 2) void k_oproj(const u16* __restrict__ A,
                                                  const u16* __restrict__ Bt,
                                                  const float* __restrict__ bias,
                                                  const float* __restrict__ res,
                                                  const float* __restrict__ alpha,
                                                  float* __restrict__ outf) {
  const int N = D_, K = D_, nk = 32;
  const int m0 = blockIdx.y * 128, n0 = blockIdx.x * 128;
  __shared__ char lds[2][32768];
  const int t = threadIdx.x;
  const int l = t & 63, w = t >> 6;
  const int wr = w >> 1, wc = w & 1;
  const int l15 = l & 15, lhi = l >> 4;
  const int sw = (l15 & 7) << 4;
  const int ab0 = l15 * 128 + ((lhi * 16) ^ sw);
  const int ab1 = l15 * 128 + ((64 + lhi * 16) ^ sw);

  auto stage = [&](int kt, int h) {
#pragma unroll
    for (int rj = 0; rj < 4; rj++) {
      const int region = rj >> 1, j = rj & 1;
      const int pl = h * 8192 + j * 4096 + t * 16;
      const int row = pl >> 7;
      const int scol = (pl & 127) ^ ((row & 7) << 4);
      const int grow = (region ? n0 : m0) + row;
      const char* src = (const char*)(region ? Bt : A) +
                        (size_t)grow * (size_t)(K * 2) + (size_t)(kt * 128 + scol);
      gload16(src, &lds[kt & 1][region * 16384 + pl]);
    }
  };

  f32x4 acc[4][4] = {};
  stage(0, 0); stage(0, 1); stage(1, 0);
  asm volatile("s_waitcnt vmcnt(4)" ::: "memory");
  __builtin_amdgcn_s_barrier();
  __builtin_amdgcn_sched_barrier(0);

  for (int kt = 0; kt < nk; ++kt) {
    const char* base = &lds[kt & 1][0];
    const char* pB0 = base + 16384 + wc * 8192 + ab0;
    const char* pB1 = base + 16384 + wc * 8192 + ab1;
    short8 bf[4][2];
#pragma unroll
    for (int ni = 0; ni < 4; ni++) {
      bf[ni][0] = *(const short8*)(pB0 + ni * 2048);
      bf[ni][1] = *(const short8*)(pB1 + ni * 2048);
    }
#pragma unroll
    for (int q = 0; q < 2; q++) {
      short8 aq[2][2];
#pragma unroll
      for (int mi = 0; mi < 2; mi++) {
        aq[mi][0] = *(const short8*)(base + q * 8192 + wr * 4096 + mi * 2048 + ab0);
        aq[mi][1] = *(const short8*)(base + q * 8192 + wr * 4096 + mi * 2048 + ab1);
      }
      if (q == 0 && kt + 1 < nk) stage(kt + 1, 1);
      if (q == 1 && kt + 2 < nk) stage(kt + 2, 0);
      __builtin_amdgcn_s_setprio(1);
#pragma unroll
      for (int ks = 0; ks < 2; ks++)
#pragma unroll
        for (int mi = 0; mi < 2; mi++)
#pragma unroll
          for (int ni = 0; ni < 4; ni++)
            acc[q * 2 + mi][ni] = __builtin_amdgcn_mfma_f32_16x16x32_bf16(
                aq[mi][ks], bf[ni][ks], acc[q * 2 + mi][ni], 0, 0, 0);
      __builtin_amdgcn_s_setprio(0);
      if (q == 0) __builtin_amdgcn_s_barrier();
    }
    if (kt + 1 < nk) {
      if (kt + 2 < nk) { asm volatile("s_waitcnt vmcnt(4)" ::: "memory"); }
      else             { asm volatile("s_waitcnt vmcnt(0)" ::: "memory"); }
      __builtin_amdgcn_s_barrier();
      __builtin_amdgcn_sched_barrier(0);
    }
  }

#pragma unroll
  for (int ni = 0; ni < 4; ni++) {
    const int col = n0 + wc * 64 + ni * 16 + l15;
    const float bcol = bias[col];
    const float alc = clipa(alpha[col]);
#pragma unroll
    for (int ai = 0; ai < 4; ai++) {
      const int row = m0 + (ai >> 1) * 64 + wr * 32 + (ai & 1) * 16 + lhi * 4;
#pragma unroll
      for (int j = 0; j < 4; j++) {
        const size_t idx = (size_t)(row + j) * N + col;
        outf[idx] = res[idx] + alc * (acc[ai][ni][j] + bcol);
      }
    }
  }
}

// out = res + clip(alpha)*(sum_z P[z] + bias) ; P is bf16
__global__ __launch_bounds__(256) void k_ffn2_combine(const u16* __restrict__ P,
                                                      const float* __restrict__ bias,
                                                      const float* __restrict__ res,
                                                      const float* __restrict__ alpha,
                                                      float* __restrict__ out) {
  const int i = blockIdx.x * 256 + threadIdx.x;
  const size_t base = (size_t)i * 8;
  const int col = (int)(base & (D_ - 1));
  const size_t PS = (size_t)M_ * D_;
  float s[8] = {};
#pragma unroll
  for (int p = 0; p < 4; p++) {
    short8 v = *(const short8*)(P + p * PS + base);
#pragma unroll
    for (int j = 0; j < 8; j++) s[j] += bf2f((u16)v[j]);
  }
  f32x4 b0 = *(const f32x4*)(bias + col);
  f32x4 b1 = *(const f32x4*)(bias + col + 4);
  f32x4 a0 = *(const f32x4*)(alpha + col);
  f32x4 a1 = *(const f32x4*)(alpha + col + 4);
  f32x4 r0 = *(const f32x4*)(res + base);
  f32x4 r1 = *(const f32x4*)(res + base + 4);
  f32x4 o0, o1;
#pragma unroll
  for (int j = 0; j < 4; j++) {
    o0[j] = r0[j] + clipa(a0[j]) * (s[j] + b0[j]);
    o1[j] = r1[j] + clipa(a1[j]) * (s[4 + j] + b1[j]);
  }
  *(f32x4*)(out + base) = o0;
  *(f32x4*)(out + base + 4) = o1;
}

// ---------------- attention: cosine attn (Q pre-scaled by tau), causal ----------------
__global__ __launch_bounds__(256) void k_attn(const u16* __restrict__ qn,
                                              const u16* __restrict__ kn,
                                              const u16* __restrict__ vn,
                                              const float* __restrict__ nu,
                                              u16* __restrict__ o) {
  __shared__ u16 Ks[64 * 128];
  __shared__ u16 Vt[128 * 64];
  __shared__ u16 Pl[4][16][72];
  const int t = threadIdx.x;
  const int l = t & 63, w = t >> 6;
  const int l15 = l & 15, lhi = l >> 4;
  const int qt = blockIdx.x;
  const int bh = blockIdx.y;
  const int h = bh & (H_ - 1);
  const int b = bh >> 4;
  const size_t hoff = (size_t)bh * S_ * DH_;
  const u16* Qh = qn + hoff;
  const u16* Kh = kn + hoff;
  const u16* Vh = vn + hoff;
  const int q0 = qt * 64;
  const int r0 = q0 + w * 16;
  short8 qf[4];
#pragma unroll
  for (int kk = 0; kk < 4; kk++)
    qf[kk] = *(const short8*)(Qh + (size_t)(r0 + l15) * DH_ + kk * 32 + lhi * 8);
  float mrow[4], lrow[4];
  f32x4 oacc[8] = {};
#pragma unroll
  for (int j = 0; j < 4; j++) { mrow[j] = -1e30f; lrow[j] = 0.f; }

  for (int kv0 = 0; kv0 < q0 + 64; kv0 += 64) {
#pragma unroll
    for (int i = 0; i < 4; i++) {
      const int p = i * 4096 + t * 16;
      const int row = p >> 8;
      const int colb = p & 255;
      const int scolb = colb ^ ((row & 7) << 4);
      gload16((const char*)(Kh + (size_t)(kv0 + row) * DH_) + scolb, (char*)Ks + p);
    }
#pragma unroll
    for (int i = 0; i < 4; i++) {
      const int c0 = w * 8 + i * 32;
      const int r = l;
      short8 vv = *(const short8*)(Vh + (size_t)(kv0 + r) * DH_ + c0);
#pragma unroll
      for (int j = 0; j < 8; j++) {
        const int ba = ((c0 + j) * 128 + r * 2) ^ (((c0 + j) & 7) << 4);
        *(u16*)((char*)Vt + ba) = (u16)vv[j];
      }
    }
    __syncthreads();
    f32x4 st[4] = {};
#pragma unroll
    for (int ks = 0; ks < 4; ks++) {
#pragma unroll
      for (int ct = 0; ct < 4; ct++) {
        const int n = ct * 16 + l15;
        const int ka = (ks * 32 + lhi * 8) * 2;
        short8 kf = *(const short8*)((const char*)Ks + n * 256 + (ka ^ ((n & 7) << 4)));
        st[ct] = __builtin_amdgcn_mfma_f32_16x16x32_bf16(qf[ks], kf, st[ct], 0, 0, 0);
      }
    }
    float pm[4] = {-1e30f, -1e30f, -1e30f, -1e30f};
#pragma unroll
    for (int ct = 0; ct < 4; ct++) {
      const int col = kv0 + ct * 16 + l15;
#pragma unroll
      for (int j = 0; j < 4; j++) {
        const int row = r0 + lhi * 4 + j;
        float s = st[ct][j];
        s = (col <= row) ? s : -1e30f;
        st[ct][j] = s;
        pm[j] = fmaxf(pm[j], s);
      }
    }
#pragma unroll
    for (int j = 0; j < 4; j++) {
#pragma unroll
      for (int off = 1; off < 16; off <<= 1) pm[j] = fmaxf(pm[j], __shfl_xor(pm[j], off));
    }
    float scl[4], psum[4];
#pragma unroll
    for (int j = 0; j < 4; j++) {
      const float nm = fmaxf(mrow[j], pm[j]);
      scl[j] = __expf(mrow[j] - nm);
      mrow[j] = nm;
      psum[j] = 0.f;
    }
#pragma unroll
    for (int ct = 0; ct < 4; ct++) {
#pragma unroll
      for (int j = 0; j < 4; j++) {
        const float p = __expf(st[ct][j] - mrow[j]);
        psum[j] += p;
        Pl[w][lhi * 4 + j][ct * 16 + l15] = f2bf(p);
      }
    }
#pragma unroll
    for (int j = 0; j < 4; j++) {
#pragma unroll
      for (int off = 1; off < 16; off <<= 1) psum[j] += __shfl_xor(psum[j], off);
      lrow[j] = lrow[j] * scl[j] + psum[j];
    }
#pragma unroll
    for (int nt = 0; nt < 8; nt++) {
#pragma unroll
      for (int j = 0; j < 4; j++) oacc[nt][j] *= scl[j];
    }
#pragma unroll
    for (int ks2 = 0; ks2 < 2; ks2++) {
      short8 pa = *(const short8*)((const char*)&Pl[w][0][0] + l15 * 144 + ks2 * 64 + lhi * 16);
#pragma unroll
      for (int nt = 0; nt < 8; nt++) {
        const int n = nt * 16 + l15;
        const int ba = (n * 128 + (ks2 * 32 + lhi * 8) * 2) ^ ((n & 7) << 4);
        short8 vf = *(const short8*)((const char*)Vt + ba);
        oacc[nt] = __builtin_amdgcn_mfma_f32_16x16x32_bf16(pa, vf, oacc[nt], 0, 0, 0);
      }
    }
    __syncthreads();
  }
  const float num = nu[h];
  float rs[4];
#pragma unroll
  for (int j = 0; j < 4; j++) rs[j] = num / lrow[j];
#pragma unroll
  for (int nt = 0; nt < 8; nt++) {
    const int col = h * DH_ + nt * 16 + l15;
#pragma unroll
    for (int j = 0; j < 4; j++) {
      const int row = r0 + lhi * 4 + j;
      o[((size_t)b * S_ + row) * D_ + col] = f2bf(oacc[nt][j] * rs[j]);
    }
  }
}

// ---------------- launch ----------------
extern "C" void kernel_launch(void* const* d_in, const int* in_sizes, int n_in,
                              void* d_out, int out_size, void* d_ws, size_t ws_size,
                              hipStream_t stream) {
  const float* x    = (const float*)d_in[0];
  const float* ln1g = (const float*)d_in[1];
  const float* ln1b = (const float*)d_in[2];
  const float* wq   = (const float*)d_in[3];
  const float* bq   = (const float*)d_in[4];
  const float* wk   = (const float*)d_in[5];
  const float* bk   = (const float*)d_in[6];
  const float* wv   = (const float*)d_in[7];
  const float* bv   = (const float*)d_in[8];
  const float* wo   = (const float*)d_in[9];
  const float* bo   = (const float*)d_in[10];
  const float* tau  = (const float*)d_in[11];
  const float* nu   = (const float*)d_in[12];
  const float* al1  = (const float*)d_in[13];
  const float* ln2g = (const float*)d_in[14];
  const float* ln2b = (const float*)d_in[15];
  const float* w1   = (const float*)d_in[16];
  const float* b1   = (const float*)d_in[17];
  const float* w2   = (const float*)d_in[18];
  const float* b2   = (const float*)d_in[19];
  const float* al2  = (const float*)d_in[20];

  char* ws = (char*)d_ws;
  u16* WQ = (u16*)(ws + 0);
  u16* WO = (u16*)(ws + 25165824);
  u16* W1B = (u16*)(ws + 33554432);
  u16* W2B = (u16*)(ws + 67108864);
  float* AF = (float*)(ws + 100663296);   // centernorm1 f32
  u16*   AB = (u16*)(ws + 117440512);     // centernorm1 bf16
  u16*   OB = (u16*)(ws + 125829120);     // attn out bf16
  u16*   MB = (u16*)(ws + 134217728);     // centernorm2 bf16
  float* X1 = (float*)(ws + 142606336);   // residual1 f32
  float* MF2 = (float*)(ws + 159383552);  // centernorm2 f32
  u16* QN = (u16*)(ws + 176160768);
  u16* KN = (u16*)(ws + 184549376);
  u16* VN = (u16*)(ws + 192937984);
  u16*   HB = (u16*)(ws + 176160768);     // ffn hidden bf16 (over QN.. after attn)
  u16*   P4 = (u16*)(ws + 0);             // ffn2 bf16 partials, 4x8MB (over WQ..WO, dead post-oproj)

  // weights -> bf16 (two one-shot halves — measured best across 8 variants)
  k_cvt_half<<<12288, 256, 0, stream>>>(wq, wk, wv, wo, w1, w2, WQ, 0);
  k_cvt_half<<<12288, 256, 0, stream>>>(wq, wk, wv, wo, w1, w2, WQ, 3145728);

  // centernorm 1
  k_centernorm<<<M_, 256, 0, stream>>>(x, ln1g, ln1b, AF, AB);

  // qkv projections + fused l2norm/tau/head-reorder -> QN/KN/VN bf16 [B,H,S,DH]
  k_qkv256<<<dim3(8, 8, 3), 512, 0, stream>>>(AB, WQ, bq, bk, bv, tau, QN, KN, VN);

  // attention (tau folded into Q)
  k_attn<<<dim3(S_ / 64, B_ * H_), 256, 0, stream>>>(QN, KN, VN, nu, OB);

  // output projection + residual (x1 = a + a1*attn)
  k_oproj<<<dim3(16, 16), 256, 0, stream>>>(OB, WO, bo, AF, al1, X1);

  // centernorm 2
  k_centernorm<<<M_, 256, 0, stream>>>(X1, ln2g, ln2b, MF2, MB);

  // ffn1 (gelu -> bf16) — r9 core
  k_ffn1_256<<<dim3(32, 8), 512, 0, stream>>>(MB, W1B, b1, HB);

  // ffn2 split-K=4 bf16 partials + combine (out = m + a2*(sum+bias)) — r9 core
  k_ffn2_256<<<dim3(8, 8, 4), 512, 0, stream>>>(HB, W2B, P4);
  k_ffn2_combine<<<2048, 256, 0, stream>>>(P4, b2, MF2, al2, (float*)d_out);
}

// Round 17
// 357.656 us; speedup vs baseline: 1.1909x; 1.0432x over previous
//
#include <hip/hip_runtime.h>
#include <hip/hip_bf16.h>
#include <stdint.h>

#define B_ 2
#define S_ 1024
#define D_ 2048
#define H_ 16
#define F_ 8192
#define DH_ 128
#define M_ 2048  // B*S

typedef unsigned short u16;
typedef __attribute__((ext_vector_type(8))) short short8;
typedef __attribute__((ext_vector_type(4))) float f32x4;

__device__ __forceinline__ u16 f2bf(float f) {
  union { float f; uint32_t u; } c; c.f = f;
  uint32_t r = c.u + 0x7FFFu + ((c.u >> 16) & 1u);
  return (u16)(r >> 16);
}

__device__ __forceinline__ float bf2f(u16 v) {
  union { uint32_t u; float f; } c; c.u = ((uint32_t)v) << 16;
  return c.f;
}

__device__ __forceinline__ void gload16(const void* g, void* l) {
  __builtin_amdgcn_global_load_lds((const __attribute__((address_space(1))) void*)g,
                                   (__attribute__((address_space(3))) void*)l, 16, 0, 0);
}

__device__ __forceinline__ float clipa(float a) {
  return fminf(0.2f, fmaxf(-0.2f, a));
}

__device__ __forceinline__ float gelu_f(float x) {
  float z = 0.7978845608028654f * (x + 0.044715f * x * x * x);
  z = fminf(10.f, fmaxf(-10.f, z));
  float e = __expf(2.f * z);
  return 0.5f * x * (1.f + (e - 1.f) / (e + 1.f));
}

// ---- fused: centernorm1 (blocks 0..2047) + WQ/WK/WV cvt (blocks 2048..8191) ----
__global__ __launch_bounds__(256) void k_cn1_cvt(const float* __restrict__ x,
                                                 const float* __restrict__ g,
                                                 const float* __restrict__ bb,
                                                 float* __restrict__ of,
                                                 u16* __restrict__ ob,
                                                 const float* __restrict__ wq,
                                                 const float* __restrict__ wk,
                                                 const float* __restrict__ wv,
                                                 u16* __restrict__ dstW) {
  if (blockIdx.x >= 2048) {
    const int gi = (blockIdx.x - 2048) * 256 + threadIdx.x;  // 0..1572863
    const int r = gi >> 19;
    const float* s = r == 0 ? wq : (r == 1 ? wk : wv);
    const int off = gi & 524287;
    f32x4 a = *(const f32x4*)(s + (size_t)off * 8);
    f32x4 b = *(const f32x4*)(s + (size_t)off * 8 + 4);
    short8 o;
    o[0] = (short)f2bf(a[0]); o[1] = (short)f2bf(a[1]);
    o[2] = (short)f2bf(a[2]); o[3] = (short)f2bf(a[3]);
    o[4] = (short)f2bf(b[0]); o[5] = (short)f2bf(b[1]);
    o[6] = (short)f2bf(b[2]); o[7] = (short)f2bf(b[3]);
    *(short8*)(dstW + (size_t)gi * 8) = o;
    return;
  }
  const int row = blockIdx.x;
  const int t = threadIdx.x;
  const float* xr = x + (size_t)row * D_;
  f32x4 v0 = *(const f32x4*)(xr + t * 8);
  f32x4 v1 = *(const f32x4*)(xr + t * 8 + 4);
  float s = v0[0] + v0[1] + v0[2] + v0[3] + v1[0] + v1[1] + v1[2] + v1[3];
#pragma unroll
  for (int off = 1; off < 64; off <<= 1) s += __shfl_xor(s, off);
  __shared__ float red[4];
  if ((t & 63) == 0) red[t >> 6] = s;
  __syncthreads();
  const float mu = (red[0] + red[1] + red[2] + red[3]) * (1.0f / D_);
  const float CNS = (float)D_ / (float)(D_ - 1);
  f32x4 g0 = *(const f32x4*)(g + t * 8);
  f32x4 g1 = *(const f32x4*)(g + t * 8 + 4);
  f32x4 b0 = *(const f32x4*)(bb + t * 8);
  f32x4 b1 = *(const f32x4*)(bb + t * 8 + 4);
  f32x4 y0, y1;
  short8 yb;
#pragma unroll
  for (int i = 0; i < 4; i++) {
    y0[i] = g0[i] * (CNS * (v0[i] - mu)) + b0[i];
    y1[i] = g1[i] * (CNS * (v1[i] - mu)) + b1[i];
  }
#pragma unroll
  for (int i = 0; i < 4; i++) { yb[i] = (short)f2bf(y0[i]); yb[4 + i] = (short)f2bf(y1[i]); }
  float* orow = of + (size_t)row * D_;
  *(f32x4*)(orow + t * 8) = y0;
  *(f32x4*)(orow + t * 8 + 4) = y1;
  *(short8*)(ob + (size_t)row * D_ + t * 8) = yb;
}

// ---------------- CenterNorm (standalone, for cn2) ----------------
__global__ __launch_bounds__(256) void k_centernorm(const float* __restrict__ x,
                                                    const float* __restrict__ g,
                                                    const float* __restrict__ bb,
                                                    float* __restrict__ of,
                                                    u16* __restrict__ ob) {
  const int row = blockIdx.x;
  const int t = threadIdx.x;
  const float* xr = x + (size_t)row * D_;
  f32x4 v0 = *(const f32x4*)(xr + t * 8);
  f32x4 v1 = *(const f32x4*)(xr + t * 8 + 4);
  float s = v0[0] + v0[1] + v0[2] + v0[3] + v1[0] + v1[1] + v1[2] + v1[3];
#pragma unroll
  for (int off = 1; off < 64; off <<= 1) s += __shfl_xor(s, off);
  __shared__ float red[4];
  if ((t & 63) == 0) red[t >> 6] = s;
  __syncthreads();
  const float mu = (red[0] + red[1] + red[2] + red[3]) * (1.0f / D_);
  const float CNS = (float)D_ / (float)(D_ - 1);
  f32x4 g0 = *(const f32x4*)(g + t * 8);
  f32x4 g1 = *(const f32x4*)(g + t * 8 + 4);
  f32x4 b0 = *(const f32x4*)(bb + t * 8);
  f32x4 b1 = *(const f32x4*)(bb + t * 8 + 4);
  f32x4 y0, y1;
  short8 yb;
#pragma unroll
  for (int i = 0; i < 4; i++) {
    y0[i] = g0[i] * (CNS * (v0[i] - mu)) + b0[i];
    y1[i] = g1[i] * (CNS * (v1[i] - mu)) + b1[i];
  }
#pragma unroll
  for (int i = 0; i < 4; i++) { yb[i] = (short)f2bf(y0[i]); yb[4 + i] = (short)f2bf(y1[i]); }
  float* orow = of + (size_t)row * D_;
  *(f32x4*)(orow + t * 8) = y0;
  *(f32x4*)(orow + t * 8 + 4) = y1;
  *(short8*)(ob + (size_t)row * D_ + t * 8) = yb;
}

// ============ 256x256 GEMM (r9 core) + optional side-channel weight cvt ============
// Side-channel (CV=true): per K-iter each thread converts one 8-float unit of a
// DIFFERENT weight matrix (independent of GEMM data; no LDS). cvt-load issued at
// top of iter (before q1 stage), cvt-store before q3 stage; sched_barrier(0) pins
// both -> end-of-tile vmcnt(4) (4 newest = q3 stage) retires tile t+1 half-1 AND
// all cvt ops: r9 hazard windows unchanged.
// EPI 2: outb=bf16(gelu(acc+bias)) ; 3: outb=bf16(acc) ; 4: fused l2norm/tau for QKV.
template <int EPI, bool CV>
__device__ __forceinline__ void gemm256_core(const u16* __restrict__ A,
                                             const u16* __restrict__ Bt,
                                             const float* __restrict__ bias,
                                             u16* __restrict__ outb,
                                             int N, int K, int kbase, int nk,
                                             int m0, int n0,
                                             const float* __restrict__ tau,
                                             u16* __restrict__ qkv, int z,
                                             const float* __restrict__ cvA,
                                             const float* __restrict__ cvB,
                                             u16* __restrict__ cvdA,
                                             u16* __restrict__ cvdB,
                                             int cvsplit, int cvtotal,
                                             int cvbf, int cvnb) {
  __shared__ char lds[2][65536];  // [buf][A 32KB | B 32KB]
  const int t = threadIdx.x;
  const int l = t & 63, w = t >> 6;
  const int wr = w >> 2, wc = w & 3;
  const int l15 = l & 15, lhi = l >> 4;
  const int sw = (l15 & 7) << 4;
  const int ab0 = l15 * 128 + ((lhi * 16) ^ sw);
  const int ab1 = l15 * 128 + ((64 + lhi * 16) ^ sw);

  auto stage = [&](int kt, int h) {
#pragma unroll
    for (int rj = 0; rj < 4; rj++) {
      const int region = rj >> 1, j = rj & 1;
      const int pl = h * 16384 + j * 8192 + t * 16;
      const int row = pl >> 7;
      const int scol = (pl & 127) ^ ((row & 7) << 4);
      const int grow = (region ? n0 : m0) + row;
      const char* src = (const char*)(region ? Bt : A) +
                        (size_t)grow * (size_t)(K * 2) +
                        (size_t)((kbase + kt * 64) * 2 + scol);
      gload16(src, &lds[kt & 1][region * 32768 + pl]);
    }
  };

  f32x4 acc[8][4] = {};

  stage(0, 0); stage(0, 1); stage(1, 0);
  asm volatile("s_waitcnt vmcnt(4)" ::: "memory");
  __builtin_amdgcn_s_barrier();
  __builtin_amdgcn_sched_barrier(0);

  for (int kt = 0; kt < nk; ++kt) {
    // side-channel cvt load (independent weight data)
    f32x4 cv0, cv1;
    u16* cdst = nullptr;
    size_t coff = 0;
    bool cdo = false;
    if (CV) {
      const int ui = (kt * cvnb + cvbf) * 512 + t;
      if (ui < cvtotal) {
        cdo = true;
        int off = ui;
        const float* csrc;
        if (off < cvsplit) { csrc = cvA; cdst = cvdA; }
        else { off -= cvsplit; csrc = cvB; cdst = cvdB; }
        coff = (size_t)off * 8;
        cv0 = *(const f32x4*)(csrc + coff);
        cv1 = *(const f32x4*)(csrc + coff + 4);
      }
      __builtin_amdgcn_sched_barrier(0);
    }
    const char* base = &lds[kt & 1][0];
    const char* pA0 = base + wr * 4096 + ab0;
    const char* pA1 = base + wr * 4096 + ab1;
    const char* pB0 = base + 32768 + wc * 8192 + ab0;
    const char* pB1 = base + 32768 + wc * 8192 + ab1;
    short8 bf[4][2];
#pragma unroll
    for (int ni = 0; ni < 4; ni++) {
      bf[ni][0] = *(const short8*)(pB0 + ni * 2048);
      bf[ni][1] = *(const short8*)(pB1 + ni * 2048);
    }
#pragma unroll
    for (int q = 0; q < 4; q++) {
      short8 aq[2][2];
#pragma unroll
      for (int mi = 0; mi < 2; mi++) {
        aq[mi][0] = *(const short8*)(pA0 + q * 8192 + mi * 2048);
        aq[mi][1] = *(const short8*)(pA1 + q * 8192 + mi * 2048);
      }
      if (q == 1 && kt + 1 < nk) stage(kt + 1, 1);
      if (q == 3) {
        if (CV && cdo) {
          short8 o;
#pragma unroll
          for (int e = 0; e < 4; e++) {
            o[e] = (short)f2bf(cv0[e]);
            o[4 + e] = (short)f2bf(cv1[e]);
          }
          *(short8*)(cdst + coff) = o;
          __builtin_amdgcn_sched_barrier(0);
        }
        if (kt + 2 < nk) stage(kt + 2, 0);
      }
      __builtin_amdgcn_s_setprio(1);
#pragma unroll
      for (int ks = 0; ks < 2; ks++)
#pragma unroll
        for (int mi = 0; mi < 2; mi++)
#pragma unroll
          for (int ni = 0; ni < 4; ni++)
            acc[q * 2 + mi][ni] = __builtin_amdgcn_mfma_f32_16x16x32_bf16(
                aq[mi][ks], bf[ni][ks], acc[q * 2 + mi][ni], 0, 0, 0);
      __builtin_amdgcn_s_setprio(0);
      if (q == 1) __builtin_amdgcn_s_barrier();
    }
    if (kt + 1 < nk) {
      if (kt + 2 < nk) { asm volatile("s_waitcnt vmcnt(4)" ::: "memory"); }
      else             { asm volatile("s_waitcnt vmcnt(0)" ::: "memory"); }
      __builtin_amdgcn_s_barrier();
      __builtin_amdgcn_sched_barrier(0);
    }
  }

  if constexpr (EPI == 4) {
    __shared__ float part[4][256];
#pragma unroll
    for (int ni = 0; ni < 4; ni++) {
      const float bc = bias[n0 + wc * 64 + ni * 16 + l15];
#pragma unroll
      for (int ai = 0; ai < 8; ai++)
#pragma unroll
        for (int j = 0; j < 4; j++) acc[ai][ni][j] += bc;
    }
    if (z < 2) {
      float p[8][4];
#pragma unroll
      for (int ai = 0; ai < 8; ai++)
#pragma unroll
        for (int j = 0; j < 4; j++) {
          p[ai][j] = acc[ai][0][j] * acc[ai][0][j] + acc[ai][1][j] * acc[ai][1][j] +
                     acc[ai][2][j] * acc[ai][2][j] + acc[ai][3][j] * acc[ai][3][j];
#pragma unroll
          for (int off = 1; off < 16; off <<= 1) p[ai][j] += __shfl_xor(p[ai][j], off);
        }
      if (l15 == 0) {
#pragma unroll
        for (int ai = 0; ai < 8; ai++)
#pragma unroll
          for (int j = 0; j < 4; j++) {
            const int rb = (ai >> 1) * 64 + wr * 32 + (ai & 1) * 16 + lhi * 4 + j;
            part[wc][rb] = p[ai][j];
          }
      }
    }
    __syncthreads();
    const int hl = wc >> 1;
    const int hglob = (n0 >> 7) + hl;
    const float tauh = (z == 0) ? tau[hglob] : 1.f;
    char* yt = (char*)&lds[0][0] + w * 16384;
#pragma unroll
    for (int ai = 0; ai < 8; ai++) {
#pragma unroll
      for (int j = 0; j < 4; j++) {
        float sc = 1.f;
        if (z < 2) {
          const int rb = (ai >> 1) * 64 + wr * 32 + (ai & 1) * 16 + lhi * 4 + j;
          const float ssq = part[2 * hl][rb] + part[2 * hl + 1][rb];
          sc = tauh / (sqrtf(ssq) + 1e-6f);
        }
        const int rl = (ai >> 1) * 32 + (ai & 1) * 16 + lhi * 4 + j;
        const int swz = (rl & 7) << 4;
#pragma unroll
        for (int ni = 0; ni < 4; ni++) {
          const int cbyte = (ni * 16 + l15) * 2;
          *(u16*)(yt + rl * 128 + (cbyte ^ swz)) = f2bf(acc[ai][ni][j] * sc);
        }
      }
    }
    __syncthreads();
#pragma unroll
    for (int pass = 0; pass < 16; pass++) {
      const int rl = pass * 8 + (l >> 3);
      const int cb = (l & 7) * 16;
      const short8 v = *(const short8*)(yt + rl * 128 + (cb ^ ((rl & 7) << 4)));
      const int m = m0 + ((rl >> 5) << 6) + wr * 32 + (rl & 31);
      const int bb2 = m >> 10, s = m & 1023;
      const int d = (wc & 1) * 64 + (cb >> 1);
      *(short8*)(qkv + (((size_t)(bb2 * H_ + hglob)) * S_ + s) * DH_ + d) = v;
    }
    return;
  }

#pragma unroll
  for (int ni = 0; ni < 4; ni++) {
    const int col = n0 + wc * 64 + ni * 16 + l15;
    const float bcol = (EPI == 3) ? 0.f : bias[col];
#pragma unroll
    for (int ai = 0; ai < 8; ai++) {
      const int row = m0 + (ai >> 1) * 64 + wr * 32 + (ai & 1) * 16 + lhi * 4;
#pragma unroll
      for (int j = 0; j < 4; j++) {
        const float v = acc[ai][ni][j] + bcol;
        const size_t idx = (size_t)(row + j) * N + col;
        if (EPI == 2) outb[idx] = f2bf(gelu_f(v));
        else outb[idx] = f2bf(v);
      }
    }
  }
}

// qkv: GEMM + side-channel cvt of WO (524288 units) + W1 (2097152 units)
__global__ __launch_bounds__(512, 2) void k_qkv256(const u16* A, const u16* W,
                                                   const float* b0, const float* b1,
                                                   const float* b2, const float* tau,
                                                   u16* qn, u16* kn, u16* vn,
                                                   const float* wo, const float* w1,
                                                   u16* WOB, u16* W1B) {
  const int z = blockIdx.z;
  const u16* Bt = W + (size_t)z * 4194304;
  const float* bias = z == 0 ? b0 : (z == 1 ? b1 : b2);
  u16* dst = z == 0 ? qn : (z == 1 ? kn : vn);
  const int bf = z * 64 + blockIdx.y * 8 + blockIdx.x;  // 0..191
  gemm256_core<4, true>(A, Bt, bias, nullptr, D_, D_, 0, 32,
                        blockIdx.y * 256, blockIdx.x * 256, tau, dst, z,
                        wo, w1, WOB, W1B, 524288, 2621440, bf, 192);
}

// ffn1: GEMM + side-channel cvt of W2 (2097152 units)
__global__ __launch_bounds__(512, 2) void k_ffn1_256(const u16* A, const u16* Bt,
                                                     const float* bias, u16* outb,
                                                     const float* w2, u16* W2B) {
  const int bf = blockIdx.y * 32 + blockIdx.x;  // 0..255
  gemm256_core<2, true>(A, Bt, bias, outb, F_, D_, 0, 32,
                        blockIdx.y * 256, blockIdx.x * 256, nullptr, nullptr, 0,
                        w2, nullptr, W2B, nullptr, 2097152, 2097152, bf, 256);
}

__global__ __launch_bounds__(512, 2) void k_ffn2_256(const u16* A, const u16* Bt, u16* P) {
  gemm256_core<3, false>(A, Bt, nullptr, P + (size_t)blockIdx.z * M_ * D_, D_, F_,
                         blockIdx.z * 2048, 32, blockIdx.y * 256, blockIdx.x * 256,
                         nullptr, nullptr, 0,
                         nullptr, nullptr, nullptr, nullptr, 0, 0, 0, 0);
}

// ---------- 128x128 deep-pipelined GEMM (4 waves): o-proj residual (r12, measured) ----------
__global__ __launch_bounds__(256, 2) void k_oproj(const u16* __restrict__ A,
                                                  const u16* __restrict__ Bt,
                                                  const float* __restrict__ bias,
                                                  const float* __restrict__ res,
                                                  const float* __restrict__ alpha,
                                                  float* __restrict__ outf) {
  const int N = D_, K = D_, nk = 32;
  const int m0 = blockIdx.y * 128, n0 = blockIdx.x * 128;
  __shared__ char lds[2][32768];
  const int t = threadIdx.x;
  const int l = t & 63, w = t >> 6;
  const int wr = w >> 1, wc = w & 1;
  const int l15 = l & 15, lhi = l >> 4;
  const int sw = (l15 & 7) << 4;
  const int ab0 = l15 * 128 + ((lhi * 16) ^ sw);
  const int ab1 = l15 * 128 + ((64 + lhi * 16) ^ sw);

  auto stage = [&](int kt, int h) {
#pragma unroll
    for (int rj = 0; rj < 4; rj++) {
      const int region = rj >> 1, j = rj & 1;
      const int pl = h * 8192 + j * 4096 + t * 16;
      const int row = pl >> 7;
      const int scol = (pl & 127) ^ ((row & 7) << 4);
      const int grow = (region ? n0 : m0) + row;
      const char* src = (const char*)(region ? Bt : A) +
                        (size_t)grow * (size_t)(K * 2) + (size_t)(kt * 128 + scol);
      gload16(src, &lds[kt & 1][region * 16384 + pl]);
    }
  };

  f32x4 acc[4][4] = {};
  stage(0, 0); stage(0, 1); stage(1, 0);
  asm volatile("s_waitcnt vmcnt(4)" ::: "memory");
  __builtin_amdgcn_s_barrier();
  __builtin_amdgcn_sched_barrier(0);

  for (int kt = 0; kt < nk; ++kt) {
    const char* base = &lds[kt & 1][0];
    const char* pB0 = base + 16384 + wc * 8192 + ab0;
    const char* pB1 = base + 16384 + wc * 8192 + ab1;
    short8 bf[4][2];
#pragma unroll
    for (int ni = 0; ni < 4; ni++) {
      bf[ni][0] = *(const short8*)(pB0 + ni * 2048);
      bf[ni][1] = *(const short8*)(pB1 + ni * 2048);
    }
#pragma unroll
    for (int q = 0; q < 2; q++) {
      short8 aq[2][2];
#pragma unroll
      for (int mi = 0; mi < 2; mi++) {
        aq[mi][0] = *(const short8*)(base + q * 8192 + wr * 4096 + mi * 2048 + ab0);
        aq[mi][1] = *(const short8*)(base + q * 8192 + wr * 4096 + mi * 2048 + ab1);
      }
      if (q == 0 && kt + 1 < nk) stage(kt + 1, 1);
      if (q == 1 && kt + 2 < nk) stage(kt + 2, 0);
      __builtin_amdgcn_s_setprio(1);
#pragma unroll
      for (int ks = 0; ks < 2; ks++)
#pragma unroll
        for (int mi = 0; mi < 2; mi++)
#pragma unroll
          for (int ni = 0; ni < 4; ni++)
            acc[q * 2 + mi][ni] = __builtin_amdgcn_mfma_f32_16x16x32_bf16(
                aq[mi][ks], bf[ni][ks], acc[q * 2 + mi][ni], 0, 0, 0);
      __builtin_amdgcn_s_setprio(0);
      if (q == 0) __builtin_amdgcn_s_barrier();
    }
    if (kt + 1 < nk) {
      if (kt + 2 < nk) { asm volatile("s_waitcnt vmcnt(4)" ::: "memory"); }
      else             { asm volatile("s_waitcnt vmcnt(0)" ::: "memory"); }
      __builtin_amdgcn_s_barrier();
      __builtin_amdgcn_sched_barrier(0);
    }
  }

#pragma unroll
  for (int ni = 0; ni < 4; ni++) {
    const int col = n0 + wc * 64 + ni * 16 + l15;
    const float bcol = bias[col];
    const float alc = clipa(alpha[col]);
#pragma unroll
    for (int ai = 0; ai < 4; ai++) {
      const int row = m0 + (ai >> 1) * 64 + wr * 32 + (ai & 1) * 16 + lhi * 4;
#pragma unroll
      for (int j = 0; j < 4; j++) {
        const size_t idx = (size_t)(row + j) * N + col;
        outf[idx] = res[idx] + alc * (acc[ai][ni][j] + bcol);
      }
    }
  }
}

// out = res + clip(alpha)*(sum_z P[z] + bias) ; P is bf16
__global__ __launch_bounds__(256) void k_ffn2_combine(const u16* __restrict__ P,
                                                      const float* __restrict__ bias,
                                                      const float* __restrict__ res,
                                                      const float* __restrict__ alpha,
                                                      float* __restrict__ out) {
  const int i = blockIdx.x * 256 + threadIdx.x;
  const size_t base = (size_t)i * 8;
  const int col = (int)(base & (D_ - 1));
  const size_t PS = (size_t)M_ * D_;
  float s[8] = {};
#pragma unroll
  for (int p = 0; p < 4; p++) {
    short8 v = *(const short8*)(P + p * PS + base);
#pragma unroll
    for (int j = 0; j < 8; j++) s[j] += bf2f((u16)v[j]);
  }
  f32x4 b0 = *(const f32x4*)(bias + col);
  f32x4 b1 = *(const f32x4*)(bias + col + 4);
  f32x4 a0 = *(const f32x4*)(alpha + col);
  f32x4 a1 = *(const f32x4*)(alpha + col + 4);
  f32x4 r0 = *(const f32x4*)(res + base);
  f32x4 r1 = *(const f32x4*)(res + base + 4);
  f32x4 o0, o1;
#pragma unroll
  for (int j = 0; j < 4; j++) {
    o0[j] = r0[j] + clipa(a0[j]) * (s[j] + b0[j]);
    o1[j] = r1[j] + clipa(a1[j]) * (s[4 + j] + b1[j]);
  }
  *(f32x4*)(out + base) = o0;
  *(f32x4*)(out + base + 4) = o1;
}

// ---------------- attention: cosine attn (Q pre-scaled by tau), causal ----------------
__global__ __launch_bounds__(256) void k_attn(const u16* __restrict__ qn,
                                              const u16* __restrict__ kn,
                                              const u16* __restrict__ vn,
                                              const float* __restrict__ nu,
                                              u16* __restrict__ o) {
  __shared__ u16 Ks[64 * 128];
  __shared__ u16 Vt[128 * 64];
  __shared__ u16 Pl[4][16][72];
  const int t = threadIdx.x;
  const int l = t & 63, w = t >> 6;
  const int l15 = l & 15, lhi = l >> 4;
  const int qt = blockIdx.x;
  const int bh = blockIdx.y;
  const int h = bh & (H_ - 1);
  const int b = bh >> 4;
  const size_t hoff = (size_t)bh * S_ * DH_;
  const u16* Qh = qn + hoff;
  const u16* Kh = kn + hoff;
  const u16* Vh = vn + hoff;
  const int q0 = qt * 64;
  const int r0 = q0 + w * 16;
  short8 qf[4];
#pragma unroll
  for (int kk = 0; kk < 4; kk++)
    qf[kk] = *(const short8*)(Qh + (size_t)(r0 + l15) * DH_ + kk * 32 + lhi * 8);
  float mrow[4], lrow[4];
  f32x4 oacc[8] = {};
#pragma unroll
  for (int j = 0; j < 4; j++) { mrow[j] = -1e30f; lrow[j] = 0.f; }

  for (int kv0 = 0; kv0 < q0 + 64; kv0 += 64) {
#pragma unroll
    for (int i = 0; i < 4; i++) {
      const int p = i * 4096 + t * 16;
      const int row = p >> 8;
      const int colb = p & 255;
      const int scolb = colb ^ ((row & 7) << 4);
      gload16((const char*)(Kh + (size_t)(kv0 + row) * DH_) + scolb, (char*)Ks + p);
    }
#pragma unroll
    for (int i = 0; i < 4; i++) {
      const int c0 = w * 8 + i * 32;
      const int r = l;
      short8 vv = *(const short8*)(Vh + (size_t)(kv0 + r) * DH_ + c0);
#pragma unroll
      for (int j = 0; j < 8; j++) {
        const int ba = ((c0 + j) * 128 + r * 2) ^ (((c0 + j) & 7) << 4);
        *(u16*)((char*)Vt + ba) = (u16)vv[j];
      }
    }
    __syncthreads();
    f32x4 st[4] = {};
#pragma unroll
    for (int ks = 0; ks < 4; ks++) {
#pragma unroll
      for (int ct = 0; ct < 4; ct++) {
        const int n = ct * 16 + l15;
        const int ka = (ks * 32 + lhi * 8) * 2;
        short8 kf = *(const short8*)((const char*)Ks + n * 256 + (ka ^ ((n & 7) << 4)));
        st[ct] = __builtin_amdgcn_mfma_f32_16x16x32_bf16(qf[ks], kf, st[ct], 0, 0, 0);
      }
    }
    float pm[4] = {-1e30f, -1e30f, -1e30f, -1e30f};
#pragma unroll
    for (int ct = 0; ct < 4; ct++) {
      const int col = kv0 + ct * 16 + l15;
#pragma unroll
      for (int j = 0; j < 4; j++) {
        const int row = r0 + lhi * 4 + j;
        float s = st[ct][j];
        s = (col <= row) ? s : -1e30f;
        st[ct][j] = s;
        pm[j] = fmaxf(pm[j], s);
      }
    }
#pragma unroll
    for (int j = 0; j < 4; j++) {
#pragma unroll
      for (int off = 1; off < 16; off <<= 1) pm[j] = fmaxf(pm[j], __shfl_xor(pm[j], off));
    }
    float scl[4], psum[4];
#pragma unroll
    for (int j = 0; j < 4; j++) {
      const float nm = fmaxf(mrow[j], pm[j]);
      scl[j] = __expf(mrow[j] - nm);
      mrow[j] = nm;
      psum[j] = 0.f;
    }
#pragma unroll
    for (int ct = 0; ct < 4; ct++) {
#pragma unroll
      for (int j = 0; j < 4; j++) {
        const float p = __expf(st[ct][j] - mrow[j]);
        psum[j] += p;
        Pl[w][lhi * 4 + j][ct * 16 + l15] = f2bf(p);
      }
    }
#pragma unroll
    for (int j = 0; j < 4; j++) {
#pragma unroll
      for (int off = 1; off < 16; off <<= 1) psum[j] += __shfl_xor(psum[j], off);
      lrow[j] = lrow[j] * scl[j] + psum[j];
    }
#pragma unroll
    for (int nt = 0; nt < 8; nt++) {
#pragma unroll
      for (int j = 0; j < 4; j++) oacc[nt][j] *= scl[j];
    }
#pragma unroll
    for (int ks2 = 0; ks2 < 2; ks2++) {
      short8 pa = *(const short8*)((const char*)&Pl[w][0][0] + l15 * 144 + ks2 * 64 + lhi * 16);
#pragma unroll
      for (int nt = 0; nt < 8; nt++) {
        const int n = nt * 16 + l15;
        const int ba = (n * 128 + (ks2 * 32 + lhi * 8) * 2) ^ ((n & 7) << 4);
        short8 vf = *(const short8*)((const char*)Vt + ba);
        oacc[nt] = __builtin_amdgcn_mfma_f32_16x16x32_bf16(pa, vf, oacc[nt], 0, 0, 0);
      }
    }
    __syncthreads();
  }
  const float num = nu[h];
  float rs[4];
#pragma unroll
  for (int j = 0; j < 4; j++) rs[j] = num / lrow[j];
#pragma unroll
  for (int nt = 0; nt < 8; nt++) {
    const int col = h * DH_ + nt * 16 + l15;
#pragma unroll
    for (int j = 0; j < 4; j++) {
      const int row = r0 + lhi * 4 + j;
      o[((size_t)b * S_ + row) * D_ + col] = f2bf(oacc[nt][j] * rs[j]);
    }
  }
}

// ---------------- launch ----------------
extern "C" void kernel_launch(void* const* d_in, const int* in_sizes, int n_in,
                              void* d_out, int out_size, void* d_ws, size_t ws_size,
                              hipStream_t stream) {
  const float* x    = (const float*)d_in[0];
  const float* ln1g = (const float*)d_in[1];
  const float* ln1b = (const float*)d_in[2];
  const float* wq   = (const float*)d_in[3];
  const float* bq   = (const float*)d_in[4];
  const float* wk   = (const float*)d_in[5];
  const float* bk   = (const float*)d_in[6];
  const float* wv   = (const float*)d_in[7];
  const float* bv   = (const float*)d_in[8];
  const float* wo   = (const float*)d_in[9];
  const float* bo   = (const float*)d_in[10];
  const float* tau  = (const float*)d_in[11];
  const float* nu   = (const float*)d_in[12];
  const float* al1  = (const float*)d_in[13];
  const float* ln2g = (const float*)d_in[14];
  const float* ln2b = (const float*)d_in[15];
  const float* w1   = (const float*)d_in[16];
  const float* b1   = (const float*)d_in[17];
  const float* w2   = (const float*)d_in[18];
  const float* b2   = (const float*)d_in[19];
  const float* al2  = (const float*)d_in[20];

  char* ws = (char*)d_ws;
  u16* WQ  = (u16*)(ws + 0);              // WQ/WK/WV bf16, 24MB
  u16* WOB = (u16*)(ws + 25165824);
  u16* W1B = (u16*)(ws + 33554432);
  u16* W2B = (u16*)(ws + 67108864);
  float* AF = (float*)(ws + 100663296);   // centernorm1 f32
  u16*   AB = (u16*)(ws + 117440512);     // centernorm1 bf16
  u16*   OB = (u16*)(ws + 125829120);     // attn out bf16
  u16*   MB = (u16*)(ws + 134217728);     // centernorm2 bf16
  float* X1 = (float*)(ws + 142606336);   // residual1 f32
  float* MF2 = (float*)(ws + 159383552);  // centernorm2 f32
  u16* QN = (u16*)(ws + 176160768);
  u16* KN = (u16*)(ws + 184549376);
  u16* VN = (u16*)(ws + 192937984);
  u16*   HB = (u16*)(ws + 176160768);     // ffn hidden bf16 (over QN.. after attn)
  u16*   P4 = (u16*)(ws + 0);             // ffn2 bf16 partials, 4x8MB (over WQ.., dead post-qkv)

  // centernorm1 + WQ/WK/WV cvt (fused)
  k_cn1_cvt<<<8192, 256, 0, stream>>>(x, ln1g, ln1b, AF, AB, wq, wk, wv, WQ);

  // qkv projections + fused l2norm/tau + side-channel cvt of WO,W1
  k_qkv256<<<dim3(8, 8, 3), 512, 0, stream>>>(AB, WQ, bq, bk, bv, tau, QN, KN, VN,
                                              wo, w1, WOB, W1B);

  // attention (tau folded into Q)
  k_attn<<<dim3(S_ / 64, B_ * H_), 256, 0, stream>>>(QN, KN, VN, nu, OB);

  // output projection + residual (x1 = a + a1*attn)
  k_oproj<<<dim3(16, 16), 256, 0, stream>>>(OB, WOB, bo, AF, al1, X1);

  // centernorm 2
  k_centernorm<<<M_, 256, 0, stream>>>(X1, ln2g, ln2b, MF2, MB);

  // ffn1 (gelu -> bf16) + side-channel cvt of W2
  k_ffn1_256<<<dim3(32, 8), 512, 0, stream>>>(MB, W1B, b1, HB, w2, W2B);

  // ffn2 split-K=4 bf16 partials + combine (out = m + a2*(sum+bias))
  k_ffn2_256<<<dim3(8, 8, 4), 512, 0, stream>>>(HB, W2B, P4);
  k_ffn2_combine<<<2048, 256, 0, stream>>>(P4, b2, MF2, al2, (float*)d_out);
}

// Round 18
// 335.547 us; speedup vs baseline: 1.2693x; 1.0659x over previous
//
#include <hip/hip_runtime.h>
#include <hip/hip_bf16.h>
#include <stdint.h>

#define B_ 2
#define S_ 1024
#define D_ 2048
#define H_ 16
#define F_ 8192
#define DH_ 128
#define M_ 2048  // B*S

typedef unsigned short u16;
typedef __attribute__((ext_vector_type(8))) short short8;
typedef __attribute__((ext_vector_type(4))) float f32x4;

__device__ __forceinline__ u16 f2bf(float f) {
  union { float f; uint32_t u; } c; c.f = f;
  uint32_t r = c.u + 0x7FFFu + ((c.u >> 16) & 1u);
  return (u16)(r >> 16);
}

__device__ __forceinline__ float bf2f(u16 v) {
  union { uint32_t u; float f; } c; c.u = ((uint32_t)v) << 16;
  return c.f;
}

__device__ __forceinline__ void gload16(const void* g, void* l) {
  __builtin_amdgcn_global_load_lds((const __attribute__((address_space(1))) void*)g,
                                   (__attribute__((address_space(3))) void*)l, 16, 0, 0);
}

__device__ __forceinline__ float clipa(float a) {
  return fminf(0.2f, fmaxf(-0.2f, a));
}

__device__ __forceinline__ float gelu_f(float x) {
  float z = 0.7978845608028654f * (x + 0.044715f * x * x * x);
  z = fminf(10.f, fmaxf(-10.f, z));
  float e = __expf(2.f * z);
  return 0.5f * x * (1.f + (e - 1.f) / (e + 1.f));
}

// ---- fused: centernorm1 (blocks 0..2047) + WQ/WK/WV cvt (blocks 2048..8191) ----
__global__ __launch_bounds__(256) void k_cn1_cvt(const float* __restrict__ x,
                                                 const float* __restrict__ g,
                                                 const float* __restrict__ bb,
                                                 float* __restrict__ of,
                                                 u16* __restrict__ ob,
                                                 const float* __restrict__ wq,
                                                 const float* __restrict__ wk,
                                                 const float* __restrict__ wv,
                                                 u16* __restrict__ dstW) {
  if (blockIdx.x >= 2048) {
    const int gi = (blockIdx.x - 2048) * 256 + threadIdx.x;  // 0..1572863
    const int r = gi >> 19;
    const float* s = r == 0 ? wq : (r == 1 ? wk : wv);
    const int off = gi & 524287;
    f32x4 a = *(const f32x4*)(s + (size_t)off * 8);
    f32x4 b = *(const f32x4*)(s + (size_t)off * 8 + 4);
    short8 o;
    o[0] = (short)f2bf(a[0]); o[1] = (short)f2bf(a[1]);
    o[2] = (short)f2bf(a[2]); o[3] = (short)f2bf(a[3]);
    o[4] = (short)f2bf(b[0]); o[5] = (short)f2bf(b[1]);
    o[6] = (short)f2bf(b[2]); o[7] = (short)f2bf(b[3]);
    *(short8*)(dstW + (size_t)gi * 8) = o;
    return;
  }
  const int row = blockIdx.x;
  const int t = threadIdx.x;
  const float* xr = x + (size_t)row * D_;
  f32x4 v0 = *(const f32x4*)(xr + t * 8);
  f32x4 v1 = *(const f32x4*)(xr + t * 8 + 4);
  float s = v0[0] + v0[1] + v0[2] + v0[3] + v1[0] + v1[1] + v1[2] + v1[3];
#pragma unroll
  for (int off = 1; off < 64; off <<= 1) s += __shfl_xor(s, off);
  __shared__ float red[4];
  if ((t & 63) == 0) red[t >> 6] = s;
  __syncthreads();
  const float mu = (red[0] + red[1] + red[2] + red[3]) * (1.0f / D_);
  const float CNS = (float)D_ / (float)(D_ - 1);
  f32x4 g0 = *(const f32x4*)(g + t * 8);
  f32x4 g1 = *(const f32x4*)(g + t * 8 + 4);
  f32x4 b0 = *(const f32x4*)(bb + t * 8);
  f32x4 b1 = *(const f32x4*)(bb + t * 8 + 4);
  f32x4 y0, y1;
  short8 yb;
#pragma unroll
  for (int i = 0; i < 4; i++) {
    y0[i] = g0[i] * (CNS * (v0[i] - mu)) + b0[i];
    y1[i] = g1[i] * (CNS * (v1[i] - mu)) + b1[i];
  }
#pragma unroll
  for (int i = 0; i < 4; i++) { yb[i] = (short)f2bf(y0[i]); yb[4 + i] = (short)f2bf(y1[i]); }
  float* orow = of + (size_t)row * D_;
  *(f32x4*)(orow + t * 8) = y0;
  *(f32x4*)(orow + t * 8 + 4) = y1;
  *(short8*)(ob + (size_t)row * D_ + t * 8) = yb;
}

// ---------------- CenterNorm (standalone, for cn2) ----------------
__global__ __launch_bounds__(256) void k_centernorm(const float* __restrict__ x,
                                                    const float* __restrict__ g,
                                                    const float* __restrict__ bb,
                                                    float* __restrict__ of,
                                                    u16* __restrict__ ob) {
  const int row = blockIdx.x;
  const int t = threadIdx.x;
  const float* xr = x + (size_t)row * D_;
  f32x4 v0 = *(const f32x4*)(xr + t * 8);
  f32x4 v1 = *(const f32x4*)(xr + t * 8 + 4);
  float s = v0[0] + v0[1] + v0[2] + v0[3] + v1[0] + v1[1] + v1[2] + v1[3];
#pragma unroll
  for (int off = 1; off < 64; off <<= 1) s += __shfl_xor(s, off);
  __shared__ float red[4];
  if ((t & 63) == 0) red[t >> 6] = s;
  __syncthreads();
  const float mu = (red[0] + red[1] + red[2] + red[3]) * (1.0f / D_);
  const float CNS = (float)D_ / (float)(D_ - 1);
  f32x4 g0 = *(const f32x4*)(g + t * 8);
  f32x4 g1 = *(const f32x4*)(g + t * 8 + 4);
  f32x4 b0 = *(const f32x4*)(bb + t * 8);
  f32x4 b1 = *(const f32x4*)(bb + t * 8 + 4);
  f32x4 y0, y1;
  short8 yb;
#pragma unroll
  for (int i = 0; i < 4; i++) {
    y0[i] = g0[i] * (CNS * (v0[i] - mu)) + b0[i];
    y1[i] = g1[i] * (CNS * (v1[i] - mu)) + b1[i];
  }
#pragma unroll
  for (int i = 0; i < 4; i++) { yb[i] = (short)f2bf(y0[i]); yb[4 + i] = (short)f2bf(y1[i]); }
  float* orow = of + (size_t)row * D_;
  *(f32x4*)(orow + t * 8) = y0;
  *(f32x4*)(orow + t * 8 + 4) = y1;
  *(short8*)(ob + (size_t)row * D_ + t * 8) = yb;
}

// ============ 256x256 GEMM (r9 core) + optional side-channel weight cvt ============
// EPI 2: outb=bf16(gelu(acc+bias)) ; 3: outb=bf16(acc) ; 4: fused l2norm/tau for QKV.
template <int EPI, bool CV>
__device__ __forceinline__ void gemm256_core(const u16* __restrict__ A,
                                             const u16* __restrict__ Bt,
                                             const float* __restrict__ bias,
                                             u16* __restrict__ outb,
                                             int N, int K, int kbase, int nk,
                                             int m0, int n0,
                                             const float* __restrict__ tau,
                                             u16* __restrict__ qkv, int z,
                                             const float* __restrict__ cvA,
                                             u16* __restrict__ cvdA,
                                             int cvtotal, int cvbf, int cvnb) {
  __shared__ char lds[2][65536];  // [buf][A 32KB | B 32KB]
  const int t = threadIdx.x;
  const int l = t & 63, w = t >> 6;
  const int wr = w >> 2, wc = w & 3;
  const int l15 = l & 15, lhi = l >> 4;
  const int sw = (l15 & 7) << 4;
  const int ab0 = l15 * 128 + ((lhi * 16) ^ sw);
  const int ab1 = l15 * 128 + ((64 + lhi * 16) ^ sw);

  auto stage = [&](int kt, int h) {
#pragma unroll
    for (int rj = 0; rj < 4; rj++) {
      const int region = rj >> 1, j = rj & 1;
      const int pl = h * 16384 + j * 8192 + t * 16;
      const int row = pl >> 7;
      const int scol = (pl & 127) ^ ((row & 7) << 4);
      const int grow = (region ? n0 : m0) + row;
      const char* src = (const char*)(region ? Bt : A) +
                        (size_t)grow * (size_t)(K * 2) +
                        (size_t)((kbase + kt * 64) * 2 + scol);
      gload16(src, &lds[kt & 1][region * 32768 + pl]);
    }
  };

  f32x4 acc[8][4] = {};

  stage(0, 0); stage(0, 1); stage(1, 0);
  asm volatile("s_waitcnt vmcnt(4)" ::: "memory");
  __builtin_amdgcn_s_barrier();
  __builtin_amdgcn_sched_barrier(0);

  for (int kt = 0; kt < nk; ++kt) {
    f32x4 cv0, cv1;
    size_t coff = 0;
    bool cdo = false;
    if (CV) {
      const int ui = (kt * cvnb + cvbf) * 512 + t;
      if (ui < cvtotal) {
        cdo = true;
        coff = (size_t)ui * 8;
        cv0 = *(const f32x4*)(cvA + coff);
        cv1 = *(const f32x4*)(cvA + coff + 4);
      }
      __builtin_amdgcn_sched_barrier(0);
    }
    const char* base = &lds[kt & 1][0];
    const char* pA0 = base + wr * 4096 + ab0;
    const char* pA1 = base + wr * 4096 + ab1;
    const char* pB0 = base + 32768 + wc * 8192 + ab0;
    const char* pB1 = base + 32768 + wc * 8192 + ab1;
    short8 bf[4][2];
#pragma unroll
    for (int ni = 0; ni < 4; ni++) {
      bf[ni][0] = *(const short8*)(pB0 + ni * 2048);
      bf[ni][1] = *(const short8*)(pB1 + ni * 2048);
    }
#pragma unroll
    for (int q = 0; q < 4; q++) {
      short8 aq[2][2];
#pragma unroll
      for (int mi = 0; mi < 2; mi++) {
        aq[mi][0] = *(const short8*)(pA0 + q * 8192 + mi * 2048);
        aq[mi][1] = *(const short8*)(pA1 + q * 8192 + mi * 2048);
      }
      if (q == 1 && kt + 1 < nk) stage(kt + 1, 1);
      if (q == 3) {
        if (CV && cdo) {
          short8 o;
#pragma unroll
          for (int e = 0; e < 4; e++) {
            o[e] = (short)f2bf(cv0[e]);
            o[4 + e] = (short)f2bf(cv1[e]);
          }
          *(short8*)(cvdA + coff) = o;
          __builtin_amdgcn_sched_barrier(0);
        }
        if (kt + 2 < nk) stage(kt + 2, 0);
      }
      __builtin_amdgcn_s_setprio(1);
#pragma unroll
      for (int ks = 0; ks < 2; ks++)
#pragma unroll
        for (int mi = 0; mi < 2; mi++)
#pragma unroll
          for (int ni = 0; ni < 4; ni++)
            acc[q * 2 + mi][ni] = __builtin_amdgcn_mfma_f32_16x16x32_bf16(
                aq[mi][ks], bf[ni][ks], acc[q * 2 + mi][ni], 0, 0, 0);
      __builtin_amdgcn_s_setprio(0);
      if (q == 1) __builtin_amdgcn_s_barrier();
    }
    if (kt + 1 < nk) {
      if (kt + 2 < nk) { asm volatile("s_waitcnt vmcnt(4)" ::: "memory"); }
      else             { asm volatile("s_waitcnt vmcnt(0)" ::: "memory"); }
      __builtin_amdgcn_s_barrier();
      __builtin_amdgcn_sched_barrier(0);
    }
  }

  if constexpr (EPI == 4) {
    __shared__ float part[4][256];
#pragma unroll
    for (int ni = 0; ni < 4; ni++) {
      const float bc = bias[n0 + wc * 64 + ni * 16 + l15];
#pragma unroll
      for (int ai = 0; ai < 8; ai++)
#pragma unroll
        for (int j = 0; j < 4; j++) acc[ai][ni][j] += bc;
    }
    if (z < 2) {
      float p[8][4];
#pragma unroll
      for (int ai = 0; ai < 8; ai++)
#pragma unroll
        for (int j = 0; j < 4; j++) {
          p[ai][j] = acc[ai][0][j] * acc[ai][0][j] + acc[ai][1][j] * acc[ai][1][j] +
                     acc[ai][2][j] * acc[ai][2][j] + acc[ai][3][j] * acc[ai][3][j];
#pragma unroll
          for (int off = 1; off < 16; off <<= 1) p[ai][j] += __shfl_xor(p[ai][j], off);
        }
      if (l15 == 0) {
#pragma unroll
        for (int ai = 0; ai < 8; ai++)
#pragma unroll
          for (int j = 0; j < 4; j++) {
            const int rb = (ai >> 1) * 64 + wr * 32 + (ai & 1) * 16 + lhi * 4 + j;
            part[wc][rb] = p[ai][j];
          }
      }
    }
    __syncthreads();
    const int hl = wc >> 1;
    const int hglob = (n0 >> 7) + hl;
    const float tauh = (z == 0) ? tau[hglob] : 1.f;
    char* yt = (char*)&lds[0][0] + w * 16384;
#pragma unroll
    for (int ai = 0; ai < 8; ai++) {
#pragma unroll
      for (int j = 0; j < 4; j++) {
        float sc = 1.f;
        if (z < 2) {
          const int rb = (ai >> 1) * 64 + wr * 32 + (ai & 1) * 16 + lhi * 4 + j;
          const float ssq = part[2 * hl][rb] + part[2 * hl + 1][rb];
          sc = tauh / (sqrtf(ssq) + 1e-6f);
        }
        const int rl = (ai >> 1) * 32 + (ai & 1) * 16 + lhi * 4 + j;
        const int swz = (rl & 7) << 4;
#pragma unroll
        for (int ni = 0; ni < 4; ni++) {
          const int cbyte = (ni * 16 + l15) * 2;
          *(u16*)(yt + rl * 128 + (cbyte ^ swz)) = f2bf(acc[ai][ni][j] * sc);
        }
      }
    }
    __syncthreads();
#pragma unroll
    for (int pass = 0; pass < 16; pass++) {
      const int rl = pass * 8 + (l >> 3);
      const int cb = (l & 7) * 16;
      const short8 v = *(const short8*)(yt + rl * 128 + (cb ^ ((rl & 7) << 4)));
      const int m = m0 + ((rl >> 5) << 6) + wr * 32 + (rl & 31);
      const int bb2 = m >> 10, s = m & 1023;
      const int d = (wc & 1) * 64 + (cb >> 1);
      *(short8*)(qkv + (((size_t)(bb2 * H_ + hglob)) * S_ + s) * DH_ + d) = v;
    }
    return;
  }

#pragma unroll
  for (int ni = 0; ni < 4; ni++) {
    const int col = n0 + wc * 64 + ni * 16 + l15;
    const float bcol = (EPI == 3) ? 0.f : bias[col];
#pragma unroll
    for (int ai = 0; ai < 8; ai++) {
      const int row = m0 + (ai >> 1) * 64 + wr * 32 + (ai & 1) * 16 + lhi * 4;
#pragma unroll
      for (int j = 0; j < 4; j++) {
        const float v = acc[ai][ni][j] + bcol;
        const size_t idx = (size_t)(row + j) * N + col;
        if (EPI == 2) outb[idx] = f2bf(gelu_f(v));
        else outb[idx] = f2bf(v);
      }
    }
  }
}

// qkv: 1D grid, 256 blocks. Blocks 0..191: GEMM (z=bid/64). Blocks 192..255: pure cvt
// of WO+W1 (2.62M units, 80/thread, 2-unit batch) riding the 64 idle CUs concurrently.
__global__ __launch_bounds__(512, 1) void k_qkv256(const u16* A, const u16* W,
                                                   const float* b0, const float* b1,
                                                   const float* b2, const float* tau,
                                                   u16* qn, u16* kn, u16* vn,
                                                   const float* wo, const float* w1,
                                                   u16* WOB, u16* W1B) {
  if (blockIdx.x >= 192) {
    const int tid = (blockIdx.x - 192) * 512 + threadIdx.x;  // 0..32767
#pragma unroll 1
    for (int it = 0; it < 40; it++) {
      int u[2];
      f32x4 a[2], b[2];
#pragma unroll
      for (int k = 0; k < 2; k++) {
        u[k] = tid + (2 * it + k) * 32768;
        const float* src = (u[k] < 524288) ? (wo + (size_t)u[k] * 8)
                                           : (w1 + (size_t)(u[k] - 524288) * 8);
        a[k] = *(const f32x4*)src;
        b[k] = *(const f32x4*)(src + 4);
      }
      __builtin_amdgcn_sched_barrier(0);
#pragma unroll
      for (int k = 0; k < 2; k++) {
        short8 o;
#pragma unroll
        for (int e = 0; e < 4; e++) {
          o[e] = (short)f2bf(a[k][e]);
          o[4 + e] = (short)f2bf(b[k][e]);
        }
        u16* dst = (u[k] < 524288) ? (WOB + (size_t)u[k] * 8)
                                   : (W1B + (size_t)(u[k] - 524288) * 8);
        *(short8*)dst = o;
      }
    }
    return;
  }
  const int z = blockIdx.x / 64;
  const int bid = blockIdx.x % 64;
  const u16* Bt = W + (size_t)z * 4194304;
  const float* bias = z == 0 ? b0 : (z == 1 ? b1 : b2);
  u16* dst = z == 0 ? qn : (z == 1 ? kn : vn);
  gemm256_core<4, false>(A, Bt, bias, nullptr, D_, D_, 0, 32,
                         (bid >> 3) * 256, (bid & 7) * 256, tau, dst, z,
                         nullptr, nullptr, 0, 0, 0);
}

// ffn1: GEMM + side-channel cvt of W2 (2097152 units) — r17-measured acceptable
__global__ __launch_bounds__(512, 2) void k_ffn1_256(const u16* A, const u16* Bt,
                                                     const float* bias, u16* outb,
                                                     const float* w2, u16* W2B) {
  const int bf = blockIdx.y * 32 + blockIdx.x;  // 0..255
  gemm256_core<2, true>(A, Bt, bias, outb, F_, D_, 0, 32,
                        blockIdx.y * 256, blockIdx.x * 256, nullptr, nullptr, 0,
                        w2, W2B, 2097152, bf, 256);
}

__global__ __launch_bounds__(512, 2) void k_ffn2_256(const u16* A, const u16* Bt, u16* P) {
  gemm256_core<3, false>(A, Bt, nullptr, P + (size_t)blockIdx.z * M_ * D_, D_, F_,
                         blockIdx.z * 2048, 32, blockIdx.y * 256, blockIdx.x * 256,
                         nullptr, nullptr, 0, nullptr, nullptr, 0, 0, 0);
}

// ---------- 128x128 deep-pipelined GEMM (4 waves): o-proj residual ----------
__global__ __launch_bounds__(256, 2) void k_oproj(const u16* __restrict__ A,
                                                  const u16* __restrict__ Bt,
                                                  const float* __restrict__ bias,
                                                  const float* __restrict__ res,
                                                  const float* __restrict__ alpha,
                                                  float* __restrict__ outf) {
  const int N = D_, K = D_, nk = 32;
  const int m0 = blockIdx.y * 128, n0 = blockIdx.x * 128;
  __shared__ char lds[2][32768];
  const int t = threadIdx.x;
  const int l = t & 63, w = t >> 6;
  const int wr = w >> 1, wc = w & 1;
  const int l15 = l & 15, lhi = l >> 4;
  const int sw = (l15 & 7) << 4;
  const int ab0 = l15 * 128 + ((lhi * 16) ^ sw);
  const int ab1 = l15 * 128 + ((64 + lhi * 16) ^ sw);

  auto stage = [&](int kt, int h) {
#pragma unroll
    for (int rj = 0; rj < 4; rj++) {
      const int region = rj >> 1, j = rj & 1;
      const int pl = h * 8192 + j * 4096 + t * 16;
      const int row = pl >> 7;
      const int scol = (pl & 127) ^ ((row & 7) << 4);
      const int grow = (region ? n0 : m0) + row;
      const char* src = (const char*)(region ? Bt : A) +
                        (size_t)grow * (size_t)(K * 2) + (size_t)(kt * 128 + scol);
      gload16(src, &lds[kt & 1][region * 16384 + pl]);
    }
  };

  f32x4 acc[4][4] = {};
  stage(0, 0); stage(0, 1); stage(1, 0);
  asm volatile("s_waitcnt vmcnt(4)" ::: "memory");
  __builtin_amdgcn_s_barrier();
  __builtin_amdgcn_sched_barrier(0);

  for (int kt = 0; kt < nk; ++kt) {
    const char* base = &lds[kt & 1][0];
    const char* pB0 = base + 16384 + wc * 8192 + ab0;
    const char* pB1 = base + 16384 + wc * 8192 + ab1;
    short8 bf[4][2];
#pragma unroll
    for (int ni = 0; ni < 4; ni++) {
      bf[ni][0] = *(const short8*)(pB0 + ni * 2048);
      bf[ni][1] = *(const short8*)(pB1 + ni * 2048);
    }
#pragma unroll
    for (int q = 0; q < 2; q++) {
      short8 aq[2][2];
#pragma unroll
      for (int mi = 0; mi < 2; mi++) {
        aq[mi][0] = *(const short8*)(base + q * 8192 + wr * 4096 + mi * 2048 + ab0);
        aq[mi][1] = *(const short8*)(base + q * 8192 + wr * 4096 + mi * 2048 + ab1);
      }
      if (q == 0 && kt + 1 < nk) stage(kt + 1, 1);
      if (q == 1 && kt + 2 < nk) stage(kt + 2, 0);
      __builtin_amdgcn_s_setprio(1);
#pragma unroll
      for (int ks = 0; ks < 2; ks++)
#pragma unroll
        for (int mi = 0; mi < 2; mi++)
#pragma unroll
          for (int ni = 0; ni < 4; ni++)
            acc[q * 2 + mi][ni] = __builtin_amdgcn_mfma_f32_16x16x32_bf16(
                aq[mi][ks], bf[ni][ks], acc[q * 2 + mi][ni], 0, 0, 0);
      __builtin_amdgcn_s_setprio(0);
      if (q == 0) __builtin_amdgcn_s_barrier();
    }
    if (kt + 1 < nk) {
      if (kt + 2 < nk) { asm volatile("s_waitcnt vmcnt(4)" ::: "memory"); }
      else             { asm volatile("s_waitcnt vmcnt(0)" ::: "memory"); }
      __builtin_amdgcn_s_barrier();
      __builtin_amdgcn_sched_barrier(0);
    }
  }

#pragma unroll
  for (int ni = 0; ni < 4; ni++) {
    const int col = n0 + wc * 64 + ni * 16 + l15;
    const float bcol = bias[col];
    const float alc = clipa(alpha[col]);
#pragma unroll
    for (int ai = 0; ai < 4; ai++) {
      const int row = m0 + (ai >> 1) * 64 + wr * 32 + (ai & 1) * 16 + lhi * 4;
#pragma unroll
      for (int j = 0; j < 4; j++) {
        const size_t idx = (size_t)(row + j) * N + col;
        outf[idx] = res[idx] + alc * (acc[ai][ni][j] + bcol);
      }
    }
  }
}

// out = res + clip(alpha)*(sum_z P[z] + bias) ; P is bf16
__global__ __launch_bounds__(256) void k_ffn2_combine(const u16* __restrict__ P,
                                                      const float* __restrict__ bias,
                                                      const float* __restrict__ res,
                                                      const float* __restrict__ alpha,
                                                      float* __restrict__ out) {
  const int i = blockIdx.x * 256 + threadIdx.x;
  const size_t base = (size_t)i * 8;
  const int col = (int)(base & (D_ - 1));
  const size_t PS = (size_t)M_ * D_;
  float s[8] = {};
#pragma unroll
  for (int p = 0; p < 4; p++) {
    short8 v = *(const short8*)(P + p * PS + base);
#pragma unroll
    for (int j = 0; j < 8; j++) s[j] += bf2f((u16)v[j]);
  }
  f32x4 b0 = *(const f32x4*)(bias + col);
  f32x4 b1 = *(const f32x4*)(bias + col + 4);
  f32x4 a0 = *(const f32x4*)(alpha + col);
  f32x4 a1 = *(const f32x4*)(alpha + col + 4);
  f32x4 r0 = *(const f32x4*)(res + base);
  f32x4 r1 = *(const f32x4*)(res + base + 4);
  f32x4 o0, o1;
#pragma unroll
  for (int j = 0; j < 4; j++) {
    o0[j] = r0[j] + clipa(a0[j]) * (s[j] + b0[j]);
    o1[j] = r1[j] + clipa(a1[j]) * (s[4 + j] + b1[j]);
  }
  *(f32x4*)(out + base) = o0;
  *(f32x4*)(out + base + 4) = o1;
}

// ---------------- attention: cosine attn (Q pre-scaled by tau), causal ----------------
__global__ __launch_bounds__(256) void k_attn(const u16* __restrict__ qn,
                                              const u16* __restrict__ kn,
                                              const u16* __restrict__ vn,
                                              const float* __restrict__ nu,
                                              u16* __restrict__ o) {
  __shared__ u16 Ks[64 * 128];
  __shared__ u16 Vt[128 * 64];
  __shared__ u16 Pl[4][16][72];
  const int t = threadIdx.x;
  const int l = t & 63, w = t >> 6;
  const int l15 = l & 15, lhi = l >> 4;
  const int qt = blockIdx.x;
  const int bh = blockIdx.y;
  const int h = bh & (H_ - 1);
  const int b = bh >> 4;
  const size_t hoff = (size_t)bh * S_ * DH_;
  const u16* Qh = qn + hoff;
  const u16* Kh = kn + hoff;
  const u16* Vh = vn + hoff;
  const int q0 = qt * 64;
  const int r0 = q0 + w * 16;
  short8 qf[4];
#pragma unroll
  for (int kk = 0; kk < 4; kk++)
    qf[kk] = *(const short8*)(Qh + (size_t)(r0 + l15) * DH_ + kk * 32 + lhi * 8);
  float mrow[4], lrow[4];
  f32x4 oacc[8] = {};
#pragma unroll
  for (int j = 0; j < 4; j++) { mrow[j] = -1e30f; lrow[j] = 0.f; }

  for (int kv0 = 0; kv0 < q0 + 64; kv0 += 64) {
#pragma unroll
    for (int i = 0; i < 4; i++) {
      const int p = i * 4096 + t * 16;
      const int row = p >> 8;
      const int colb = p & 255;
      const int scolb = colb ^ ((row & 7) << 4);
      gload16((const char*)(Kh + (size_t)(kv0 + row) * DH_) + scolb, (char*)Ks + p);
    }
#pragma unroll
    for (int i = 0; i < 4; i++) {
      const int c0 = w * 8 + i * 32;
      const int r = l;
      short8 vv = *(const short8*)(Vh + (size_t)(kv0 + r) * DH_ + c0);
#pragma unroll
      for (int j = 0; j < 8; j++) {
        const int ba = ((c0 + j) * 128 + r * 2) ^ (((c0 + j) & 7) << 4);
        *(u16*)((char*)Vt + ba) = (u16)vv[j];
      }
    }
    __syncthreads();
    f32x4 st[4] = {};
#pragma unroll
    for (int ks = 0; ks < 4; ks++) {
#pragma unroll
      for (int ct = 0; ct < 4; ct++) {
        const int n = ct * 16 + l15;
        const int ka = (ks * 32 + lhi * 8) * 2;
        short8 kf = *(const short8*)((const char*)Ks + n * 256 + (ka ^ ((n & 7) << 4)));
        st[ct] = __builtin_amdgcn_mfma_f32_16x16x32_bf16(qf[ks], kf, st[ct], 0, 0, 0);
      }
    }
    float pm[4] = {-1e30f, -1e30f, -1e30f, -1e30f};
#pragma unroll
    for (int ct = 0; ct < 4; ct++) {
      const int col = kv0 + ct * 16 + l15;
#pragma unroll
      for (int j = 0; j < 4; j++) {
        const int row = r0 + lhi * 4 + j;
        float s = st[ct][j];
        s = (col <= row) ? s : -1e30f;
        st[ct][j] = s;
        pm[j] = fmaxf(pm[j], s);
      }
    }
#pragma unroll
    for (int j = 0; j < 4; j++) {
#pragma unroll
      for (int off = 1; off < 16; off <<= 1) pm[j] = fmaxf(pm[j], __shfl_xor(pm[j], off));
    }
    float scl[4], psum[4];
#pragma unroll
    for (int j = 0; j < 4; j++) {
      const float nm = fmaxf(mrow[j], pm[j]);
      scl[j] = __expf(mrow[j] - nm);
      mrow[j] = nm;
      psum[j] = 0.f;
    }
#pragma unroll
    for (int ct = 0; ct < 4; ct++) {
#pragma unroll
      for (int j = 0; j < 4; j++) {
        const float p = __expf(st[ct][j] - mrow[j]);
        psum[j] += p;
        Pl[w][lhi * 4 + j][ct * 16 + l15] = f2bf(p);
      }
    }
#pragma unroll
    for (int j = 0; j < 4; j++) {
#pragma unroll
      for (int off = 1; off < 16; off <<= 1) psum[j] += __shfl_xor(psum[j], off);
      lrow[j] = lrow[j] * scl[j] + psum[j];
    }
#pragma unroll
    for (int nt = 0; nt < 8; nt++) {
#pragma unroll
      for (int j = 0; j < 4; j++) oacc[nt][j] *= scl[j];
    }
#pragma unroll
    for (int ks2 = 0; ks2 < 2; ks2++) {
      short8 pa = *(const short8*)((const char*)&Pl[w][0][0] + l15 * 144 + ks2 * 64 + lhi * 16);
#pragma unroll
      for (int nt = 0; nt < 8; nt++) {
        const int n = nt * 16 + l15;
        const int ba = (n * 128 + (ks2 * 32 + lhi * 8) * 2) ^ ((n & 7) << 4);
        short8 vf = *(const short8*)((const char*)Vt + ba);
        oacc[nt] = __builtin_amdgcn_mfma_f32_16x16x32_bf16(pa, vf, oacc[nt], 0, 0, 0);
      }
    }
    __syncthreads();
  }
  const float num = nu[h];
  float rs[4];
#pragma unroll
  for (int j = 0; j < 4; j++) rs[j] = num / lrow[j];
#pragma unroll
  for (int nt = 0; nt < 8; nt++) {
    const int col = h * DH_ + nt * 16 + l15;
#pragma unroll
    for (int j = 0; j < 4; j++) {
      const int row = r0 + lhi * 4 + j;
      o[((size_t)b * S_ + row) * D_ + col] = f2bf(oacc[nt][j] * rs[j]);
    }
  }
}

// ---------------- launch ----------------
extern "C" void kernel_launch(void* const* d_in, const int* in_sizes, int n_in,
                              void* d_out, int out_size, void* d_ws, size_t ws_size,
                              hipStream_t stream) {
  const float* x    = (const float*)d_in[0];
  const float* ln1g = (const float*)d_in[1];
  const float* ln1b = (const float*)d_in[2];
  const float* wq   = (const float*)d_in[3];
  const float* bq   = (const float*)d_in[4];
  const float* wk   = (const float*)d_in[5];
  const float* bk   = (const float*)d_in[6];
  const float* wv   = (const float*)d_in[7];
  const float* bv   = (const float*)d_in[8];
  const float* wo   = (const float*)d_in[9];
  const float* bo   = (const float*)d_in[10];
  const float* tau  = (const float*)d_in[11];
  const float* nu   = (const float*)d_in[12];
  const float* al1  = (const float*)d_in[13];
  const float* ln2g = (const float*)d_in[14];
  const float* ln2b = (const float*)d_in[15];
  const float* w1   = (const float*)d_in[16];
  const float* b1   = (const float*)d_in[17];
  const float* w2   = (const float*)d_in[18];
  const float* b2   = (const float*)d_in[19];
  const float* al2  = (const float*)d_in[20];

  char* ws = (char*)d_ws;
  u16* WQ  = (u16*)(ws + 0);              // WQ/WK/WV bf16, 24MB
  u16* WOB = (u16*)(ws + 25165824);
  u16* W1B = (u16*)(ws + 33554432);
  u16* W2B = (u16*)(ws + 67108864);
  float* AF = (float*)(ws + 100663296);   // centernorm1 f32
  u16*   AB = (u16*)(ws + 117440512);     // centernorm1 bf16
  u16*   OB = (u16*)(ws + 125829120);     // attn out bf16
  u16*   MB = (u16*)(ws + 134217728);     // centernorm2 bf16
  float* X1 = (float*)(ws + 142606336);   // residual1 f32
  float* MF2 = (float*)(ws + 159383552);  // centernorm2 f32
  u16* QN = (u16*)(ws + 176160768);
  u16* KN = (u16*)(ws + 184549376);
  u16* VN = (u16*)(ws + 192937984);
  u16*   HB = (u16*)(ws + 176160768);     // ffn hidden bf16 (over QN.. after attn)
  u16*   P4 = (u16*)(ws + 0);             // ffn2 bf16 partials, 4x8MB (over WQ.., dead post-qkv)

  // centernorm1 + WQ/WK/WV cvt (fused)
  k_cn1_cvt<<<8192, 256, 0, stream>>>(x, ln1g, ln1b, AF, AB, wq, wk, wv, WQ);

  // qkv (192 GEMM blocks) + 64 concurrent cvt blocks for WO,W1 on the idle CUs
  k_qkv256<<<256, 512, 0, stream>>>(AB, WQ, bq, bk, bv, tau, QN, KN, VN,
                                    wo, w1, WOB, W1B);

  // attention (tau folded into Q)
  k_attn<<<dim3(S_ / 64, B_ * H_), 256, 0, stream>>>(QN, KN, VN, nu, OB);

  // output projection + residual (x1 = a + a1*attn)
  k_oproj<<<dim3(16, 16), 256, 0, stream>>>(OB, WOB, bo, AF, al1, X1);

  // centernorm 2
  k_centernorm<<<M_, 256, 0, stream>>>(X1, ln2g, ln2b, MF2, MB);

  // ffn1 (gelu -> bf16) + side-channel cvt of W2
  k_ffn1_256<<<dim3(32, 8), 512, 0, stream>>>(MB, W1B, b1, HB, w2, W2B);

  // ffn2 split-K=4 bf16 partials + combine (out = m + a2*(sum+bias))
  k_ffn2_256<<<dim3(8, 8, 4), 512, 0, stream>>>(HB, W2B, P4);
  k_ffn2_combine<<<2048, 256, 0, stream>>>(P4, b2, MF2, al2, (float*)d_out);
}